// Round 8
// baseline (7787.475 us; speedup 1.0000x reference)
//
#include <hip/hip_runtime.h>
#include <math.h>

typedef unsigned short u16;
typedef __attribute__((ext_vector_type(8))) short bf16x8;
typedef __attribute__((ext_vector_type(4))) float f32x4;
typedef __attribute__((ext_vector_type(2))) _Float16 f16x2;

#define T_STEPS 64
#define B_      256
#define EMB_    1024
#define ACT_    6
#define STOCH_  64
#define HID_    512
#define FEAT_   512
#define STATE_  576
#define G3      1536
#define LOG2PI_ 1.8378770664093453

struct Params {
  const float *emb,*action,*reward,*eps;
  const float *bih,*bhh,*stb0,*stb1,*stb2,*epb0,*epb1,*epb2;
  const u16 *hWih,*hWhh,*hstW0h,*hstW1,*hstW2;   // f16 scan weights
  const u16 *eprec;       // bf16 [T*B][512]: precomputed emb_prev @ stW0[:,512:]^T
  u16 *states;            // bf16 [T*B][STATE_]
  float *qraw;            // [T*B][128]: qmu(64) | qstd(64, post-softplus)
  double *acc;            // [0]=kl [1]=emb [2]=reward
  float *out;
};

__device__ __forceinline__ float4 ld4(const float* p){ return *(const float4*)p; }
__device__ __forceinline__ float elu_f(float x){ return x > 0.f ? x : expm1f(x); }
__device__ __forceinline__ float sigmoid_f(float x){ return 1.f/(1.f+expf(-x)); }
__device__ __forceinline__ float softplus_f(float x){ return x > 20.f ? x : log1pf(expf(x)); }
__device__ __forceinline__ float blo(unsigned u){ return __uint_as_float(u << 16); }
__device__ __forceinline__ float bhi(unsigned u){ return __uint_as_float(u & 0xFFFF0000u); }
__device__ __forceinline__ float bf2f(u16 v){ return __uint_as_float((unsigned)v << 16); }
__device__ __forceinline__ u16 f2bf(float x){     // fp32 -> bf16 RNE
  const unsigned u = __float_as_uint(x);
  return (u16)((u + 0x7FFFu + ((u>>16)&1u)) >> 16);
}
__device__ __forceinline__ u16 f2h(float x){ _Float16 h = (_Float16)x; union{_Float16 h; u16 u;} c; c.h = h; return c.u; }
__device__ __forceinline__ float h2f(u16 v){ union{u16 u; _Float16 h;} c; c.u = v; return (float)c.h; }
__device__ __forceinline__ f16x2 asf2(unsigned u){ union{unsigned u; f16x2 v;} c; c.u = u; return c.v; }
__device__ __forceinline__ float qred(float a){   // reduce over 4-lane cluster
  a += __shfl_xor(a, 1, 64);
  a += __shfl_xor(a, 2, 64);
  return a;
}
__device__ __forceinline__ double wave_sum(double v){
  #pragma unroll
  for (int o = 32; o > 0; o >>= 1) v += __shfl_down(v, o, 64);
  return v;
}

// ---------------- weight converters ----------------
__global__ void convw_k(const float* __restrict__ s, u16* __restrict__ d, int n){
  const int i = blockIdx.x*256 + threadIdx.x;
  if (i < n){
    const unsigned u = __float_as_uint(s[i]);
    d[i] = (u16)((u + 0x7FFFu + ((u>>16)&1u)) >> 16);
  }
}
// fp32 -> f16 (RNE)
__global__ void convh_k(const float* __restrict__ s, u16* __restrict__ d, int n){
  const int i = blockIdx.x*256 + threadIdx.x;
  if (i < n) d[i] = f2h(s[i]);
}
// Wih [1536][70] -> padded [1536][96] f16 (zero pad)
__global__ void convhih_k(const float* __restrict__ s, u16* __restrict__ d){
  const int i = blockIdx.x*256 + threadIdx.x;   // < 1536*96
  const int n = i/96, k = i%96;
  d[i] = (k < 70) ? f2h(s[n*70 + k]) : (u16)0;
}
// stW0 h-head: [512][1536] -> packed [512][512] f16 (cols 0..511)
__global__ void convh_sub_k(const float* __restrict__ s, u16* __restrict__ d){
  const int i = blockIdx.x*256 + threadIdx.x;   // < 512*512
  if (i < 512*512){
    const int n = i >> 9, k = i & 511;
    d[i] = f2h(s[(long)n*G3 + k]);
  }
}

// ---------------- multi-stream f16 GEMV core (R13) ----------------
// NS independent weight streams per 4-lane cluster (rows c + s*RS), one shared x.
// 1 fp32 accumulator + 1 pointer per stream -> NS-deep load MLP per wave.
template<int NS, int K, int RS>
__device__ __forceinline__ void gemvNS(const u16* __restrict__ W, const u16* __restrict__ x,
                                       int c, int l, float* y){
  const u16* xr = x + l*8;
  const u16* wp[NS];
  float acc[NS];
  #pragma unroll
  for (int s = 0; s < NS; ++s){ wp[s] = W + (long)(c + s*RS)*K + l*8; acc[s] = 0.f; }
  #pragma unroll
  for (int j = 0; j < K/32; ++j){
    const uint4 xv = *(const uint4*)(xr + 32*j);
    #pragma unroll
    for (int s = 0; s < NS; ++s){
      const uint4 a = *(const uint4*)(wp[s] + 32*j);
      acc[s] = __builtin_amdgcn_fdot2(asf2(a.x), asf2(xv.x), acc[s], false);
      acc[s] = __builtin_amdgcn_fdot2(asf2(a.y), asf2(xv.y), acc[s], false);
      acc[s] = __builtin_amdgcn_fdot2(asf2(a.z), asf2(xv.z), acc[s], false);
      acc[s] = __builtin_amdgcn_fdot2(asf2(a.w), asf2(xv.w), acc[s], false);
    }
  }
  #pragma unroll
  for (int s = 0; s < NS; ++s) y[s] = qred(acc[s]);
}

// ---------------- scan kernel: 1024 thr, merged gh+st0 phase (R13) -----------------
// R12 was latency-bound (VALUBusy 14.7%, VGPR 64 -> ~6 loads in flight/wave).
// R13: gh_next = Whh@h_t computed in the SAME phase as st0's h-head (both read h_t)
// -> the phase carrying 2/3 of weight bytes runs 8 streams deep; gh parked in LDS
// for step t+1 (t=0 seeded gh=bhh). a_{t+1} prefetch folded into sample phase.
__global__ void __launch_bounds__(1024) scan_kernel(Params p)
{
  const int tid = threadIdx.x;
  const int r = blockIdx.x;
  const int c = tid >> 2, l = tid & 3;   // 256 clusters of 4 lanes

  __shared__ __align__(16) u16 hsh[512];       // f16 h
  __shared__ __align__(16) u16 sah[96];        // f16 [s(64) | a(6) | 0-pad]
  __shared__ __align__(16) float gi[G3], gh[G3];
  __shared__ __align__(16) u16 po0h[512], po1h[512];   // f16
  __shared__ __align__(16) float po2[128];

  if (tid < 512) hsh[tid] = 0;
  if (tid < 96)  sah[tid] = 0;
  if (tid < 6)   sah[64 + tid] = f2h(p.action[((long)0*B_ + r)*ACT_ + tid]);
  for (int i = tid; i < G3; i += 1024) gh[i] = p.bhh[i];   // gh(0) = Whh@0 + bhh
  __syncthreads();

  for (int t = 0; t < T_STEPS; ++t){
    // ---- P1: gi = Wih@[s_{t-1}|a_t] (6 streams, K=96) ----
    {
      float y[6];
      gemvNS<6, 96, 256>(p.hWih, sah, c, l, y);
      if (l == 0){
        #pragma unroll
        for (int s = 0; s < 6; ++s){
          const int n = c + s*256;
          gi[n] = y[s] + p.bih[n];
        }
      }
    }
    __syncthreads();
    // ---- GRU combine -> h_t (gh from previous iteration's P2; biases included) ----
    if (tid < 512){
      const int j = tid;
      const float ir = gi[j], iz = gi[512+j], in_ = gi[1024+j];
      const float hr = gh[j], hz = gh[512+j], hn  = gh[1024+j];
      const float rr = sigmoid_f(ir + hr);
      const float z  = sigmoid_f(iz + hz);
      const float nn = tanhf(in_ + rr*hn);
      const float hv = (1.f - z)*nn + z*h2f(hsh[j]);
      hsh[j] = f2h(hv);
      p.states[((long)t*B_ + r)*STATE_ + j] = f2bf(hv);
    }
    __syncthreads();
    // ---- P2 (fat phase, 8 streams): st0 h-head + gh_next = Whh@h_t ----
    {
      float y[2];
      gemvNS<2, 512, 256>(p.hstW0h, hsh, c, l, y);
      if (l == 0){
        const u16* ep = p.eprec + ((long)t*B_ + r)*512;
        #pragma unroll
        for (int s = 0; s < 2; ++s){
          const int n = c + s*256;
          po0h[n] = f2h(elu_f(y[s] + p.stb0[n] + bf2f(ep[n])));
        }
      }
    }
    {
      float y[6];
      gemvNS<6, 512, 256>(p.hWhh, hsh, c, l, y);
      if (l == 0){
        #pragma unroll
        for (int s = 0; s < 6; ++s){
          const int n = c + s*256;
          gh[n] = y[s] + p.bhh[n];
        }
      }
    }
    __syncthreads();
    // ---- st1 posterior ----
    {
      float y[2];
      gemvNS<2, 512, 256>(p.hstW1, po0h, c, l, y);
      if (l == 0){
        #pragma unroll
        for (int s = 0; s < 2; ++s){
          const int n = c + s*256;
          po1h[n] = f2h(elu_f(y[s] + p.stb1[n]));
        }
      }
    }
    __syncthreads();
    // ---- st2 posterior (clusters 0..63) ----
    if (c < 64){
      float y[2];
      gemvNS<2, 512, 64>(p.hstW2, po1h, c, l, y);
      if (l == 0){
        po2[c]      = y[0] + p.stb2[c];
        po2[c + 64] = y[1] + p.stb2[c + 64];
      }
    }
    __syncthreads();
    // ---- sample s_t + a_{t+1} prefetch ----
    if (tid < 64){
      const int j = tid;
      const float qmu = po2[j],  qsr = po2[64+j];
      const float qstd = softplus_f(qsr) + 1e-4f;
      const float sv = qmu + qstd * p.eps[((long)t*B_ + r)*STOCH_ + j];
      sah[j] = f2h(sv);
      p.states[((long)t*B_ + r)*STATE_ + 512 + j] = f2bf(sv);
      p.qraw[((long)t*B_ + r)*128 + j]      = qmu;
      p.qraw[((long)t*B_ + r)*128 + 64 + j] = qstd;
    } else if (tid < 70 && t + 1 < T_STEPS){
      sah[tid] = f2h(p.action[((long)(t+1)*B_ + r)*ACT_ + (tid - 64)]);
    }
    __syncthreads();
  }
}

// ---------------- epre GEMM: emb_prev (fp32, in-reg cvt) @ stW0[:,512:]^T -> bf16 ----
__global__ void __launch_bounds__(256) gemm_epre_k(const float* __restrict__ E,
                                                   const u16* __restrict__ W,   // bstW0 full
                                                   u16* __restrict__ Y)
{
  const int NT = 4;
  const int tid = threadIdx.x;
  const int wave = tid >> 6, lane = tid & 63;
  const int bm = blockIdx.x / NT, bn = blockIdx.x % NT;
  const int row0 = bm*128 + ((wave>>1)<<6);
  const int col0 = bn*128 + ((wave&1)<<6);
  const int lr = lane & 15, lk = (lane >> 4) * 8;
  f32x4 acc[4][4] = {};
  for (int k0 = 0; k0 < EMB_; k0 += 32){
    bf16x8 a[4], b[4];
    #pragma unroll
    for (int i = 0; i < 4; ++i){
      const int row = row0 + 16*i + lr;
      const int arow = row - (row >= B_ ? B_ : 0);   // emb_prev shift (128-blocks never straddle)
      const float* src = E + (long)arow*EMB_ + k0 + lk;
      const float4 f0 = ld4(src), f1 = ld4(src + 4);
      bf16x8 v;
      v[0] = (short)f2bf(f0.x); v[1] = (short)f2bf(f0.y);
      v[2] = (short)f2bf(f0.z); v[3] = (short)f2bf(f0.w);
      v[4] = (short)f2bf(f1.x); v[5] = (short)f2bf(f1.y);
      v[6] = (short)f2bf(f1.z); v[7] = (short)f2bf(f1.w);
      a[i] = v;
    }
    #pragma unroll
    for (int j = 0; j < 4; ++j)
      b[j] = *(const bf16x8*)(W + (long)(col0+16*j+lr)*G3 + 512 + k0 + lk);
    #pragma unroll
    for (int i = 0; i < 4; ++i)
      #pragma unroll
      for (int j = 0; j < 4; ++j)
        acc[i][j] = __builtin_amdgcn_mfma_f32_16x16x32_bf16(a[i], b[j], acc[i][j], 0, 0, 0);
  }
  #pragma unroll
  for (int j = 0; j < 4; ++j){
    const int col = col0 + 16*j + lr;
    #pragma unroll
    for (int i = 0; i < 4; ++i)
      #pragma unroll
      for (int q = 0; q < 4; ++q){
        const int row = row0 + 16*i + (lane>>4)*4 + q;
        Y[(long)row*512 + col] = f2bf(acc[i][j][q]);
      }
  }
}

// ---------------- MFMA bf16 tail GEMMs (R10-proven, byte-identical) -----------------

__global__ void __launch_bounds__(256) gemm_h_k(const u16* __restrict__ A,
                                                const u16* __restrict__ W,
                                                const float* __restrict__ bias,
                                                u16* __restrict__ Y,
                                                int NT, int K, int act, int zlo)
{
  const int tid = threadIdx.x;
  const int wave = tid >> 6, lane = tid & 63;
  const int bm = blockIdx.x / NT, bn = blockIdx.x % NT;
  const int row0 = bm*128 + ((wave>>1)<<6);
  const int col0 = bn*128 + ((wave&1)<<6);
  const int lr = lane & 15, lk = (lane >> 4) * 8;
  const int N = NT << 7;
  f32x4 acc[4][4] = {};
  const u16* Ab = A + (long)row0*K + lk;
  const u16* Wb = W + (long)col0*K + lk;
  const bf16x8 zf = {};
  for (int k0 = 0; k0 < K; k0 += 32){
    bf16x8 a[4], b[4];
    #pragma unroll
    for (int i = 0; i < 4; ++i)
      a[i] = (row0 + 16*i >= zlo) ? *(const bf16x8*)(Ab + (long)(16*i+lr)*K + k0) : zf;
    #pragma unroll
    for (int j = 0; j < 4; ++j) b[j] = *(const bf16x8*)(Wb + (long)(16*j+lr)*K + k0);
    #pragma unroll
    for (int i = 0; i < 4; ++i)
      #pragma unroll
      for (int j = 0; j < 4; ++j)
        acc[i][j] = __builtin_amdgcn_mfma_f32_16x16x32_bf16(a[i], b[j], acc[i][j], 0, 0, 0);
  }
  #pragma unroll
  for (int j = 0; j < 4; ++j){
    const int col = col0 + 16*j + lr;
    const float bv = bias[col];
    #pragma unroll
    for (int i = 0; i < 4; ++i){
      #pragma unroll
      for (int q = 0; q < 4; ++q){
        const int row = row0 + 16*i + (lane>>4)*4 + q;
        float v = acc[i][j][q] + bv;
        if (act) v = elu_f(v);
        Y[(long)row*N + col] = f2bf(v);
      }
    }
  }
}

// st0 prior: A = [states.h (ld 576, k<512) | pemb (ld 1024, k>=512)], W [512][1536], elu out
__global__ void __launch_bounds__(256) gemm_cat_k(const u16* __restrict__ A1,
                                                  const u16* __restrict__ A2,
                                                  const u16* __restrict__ W,
                                                  const float* __restrict__ bias,
                                                  u16* __restrict__ Y)
{
  const int NT = 4;
  const int tid = threadIdx.x;
  const int wave = tid >> 6, lane = tid & 63;
  const int bm = blockIdx.x / NT, bn = blockIdx.x % NT;
  const int row0 = bm*128 + ((wave>>1)<<6);
  const int col0 = bn*128 + ((wave&1)<<6);
  const int lr = lane & 15, lk = (lane >> 4) * 8;
  f32x4 acc[4][4] = {};
  for (int k0 = 0; k0 < G3; k0 += 32){
    bf16x8 a[4], b[4];
    #pragma unroll
    for (int i = 0; i < 4; ++i){
      const long row = row0 + 16*i + lr;
      a[i] = (k0 < 512) ? *(const bf16x8*)(A1 + row*STATE_ + k0 + lk)
                        : *(const bf16x8*)(A2 + row*EMB_ + (k0-512) + lk);
    }
    #pragma unroll
    for (int j = 0; j < 4; ++j)
      b[j] = *(const bf16x8*)(W + (long)(col0+16*j+lr)*G3 + k0 + lk);
    #pragma unroll
    for (int i = 0; i < 4; ++i)
      #pragma unroll
      for (int j = 0; j < 4; ++j)
        acc[i][j] = __builtin_amdgcn_mfma_f32_16x16x32_bf16(a[i], b[j], acc[i][j], 0, 0, 0);
  }
  #pragma unroll
  for (int j = 0; j < 4; ++j){
    const int col = col0 + 16*j + lr;
    const float bv = bias[col];
    #pragma unroll
    for (int i = 0; i < 4; ++i){
      #pragma unroll
      for (int q = 0; q < 4; ++q){
        const int row = row0 + 16*i + (lane>>4)*4 + q;
        Y[(long)row*FEAT_ + col] = f2bf(elu_f(acc[i][j][q] + bv));
      }
    }
  }
}

// st2 prior: N=128, K=512, raw f32 out (+bias, no act). grid = M/128 blocks.
__global__ void __launch_bounds__(256) gemm_raw_k(const u16* __restrict__ A,
                                                  const u16* __restrict__ W,
                                                  const float* __restrict__ bias,
                                                  float* __restrict__ Y)
{
  const int tid = threadIdx.x;
  const int wave = tid >> 6, lane = tid & 63;
  const int row0 = blockIdx.x*128 + ((wave>>1)<<6);
  const int col0 = (wave&1)<<6;
  const int lr = lane & 15, lk = (lane >> 4) * 8;
  f32x4 acc[4][4] = {};
  const u16* Ab = A + (long)row0*FEAT_ + lk;
  const u16* Wb = W + (long)col0*FEAT_ + lk;
  for (int k0 = 0; k0 < FEAT_; k0 += 32){
    bf16x8 a[4], b[4];
    #pragma unroll
    for (int i = 0; i < 4; ++i) a[i] = *(const bf16x8*)(Ab + (long)(16*i+lr)*FEAT_ + k0);
    #pragma unroll
    for (int j = 0; j < 4; ++j) b[j] = *(const bf16x8*)(Wb + (long)(16*j+lr)*FEAT_ + k0);
    #pragma unroll
    for (int i = 0; i < 4; ++i)
      #pragma unroll
      for (int j = 0; j < 4; ++j)
        acc[i][j] = __builtin_amdgcn_mfma_f32_16x16x32_bf16(a[i], b[j], acc[i][j], 0, 0, 0);
  }
  #pragma unroll
  for (int j = 0; j < 4; ++j){
    const int col = col0 + 16*j + lr;
    const float bv = bias[col];
    #pragma unroll
    for (int i = 0; i < 4; ++i){
      #pragma unroll
      for (int q = 0; q < 4; ++q){
        const int row = row0 + 16*i + (lane>>4)*4 + q;
        Y[(long)row*128 + col] = acc[i][j][q] + bv;
      }
    }
  }
}

// KL over one 4096-row chunk: q = stored qmu/qstd, pr = prior raw (pmu, psr).
__global__ void __launch_bounds__(512) kl_k(const float* __restrict__ q,
                                            const float* __restrict__ pr,
                                            double* accp)
{
  const int idx = blockIdx.x*512 + threadIdx.x;   // < 4096*64
  const int row = idx >> 6, j = idx & 63;
  const float qmu = q[row*128 + j], qstd = q[row*128 + 64 + j];
  const float pmu = pr[row*128 + j], psr = pr[row*128 + 64 + j];
  const float pstd = softplus_f(psr) + 1e-4f;
  const float dm = qmu - pmu;
  double v = (double)(logf(pstd/qstd) + (qstd*qstd + dm*dm)/(2.f*pstd*pstd) - 0.5f);
  v = wave_sum(v);
  if ((threadIdx.x & 63) == 0) atomicAdd(accp, v);
}

__device__ __forceinline__ double wave_sum_d(double v){
  #pragma unroll
  for (int o = 32; o > 0; o >>= 1) v += __shfl_down(v, o, 64);
  return v;
}

__global__ void __launch_bounds__(256) gemm_loss_k(const u16* __restrict__ A,
                                                   const u16* __restrict__ W,
                                                   const float* __restrict__ bias,
                                                   const float* __restrict__ tgt,
                                                   int NT, int K, double* accp)
{
  const int tid = threadIdx.x;
  const int wave = tid >> 6, lane = tid & 63;
  const int bm = blockIdx.x / NT, bn = blockIdx.x % NT;
  const int row0 = bm*128 + ((wave>>1)<<6);
  const int col0 = bn*128 + ((wave&1)<<6);
  const int lr = lane & 15, lk = (lane >> 4) * 8;
  const int N = NT << 7;
  f32x4 acc[4][4] = {};
  const u16* Ab = A + (long)row0*K + lk;
  const u16* Wb = W + (long)col0*K + lk;
  for (int k0 = 0; k0 < K; k0 += 32){
    bf16x8 a[4], b[4];
    #pragma unroll
    for (int i = 0; i < 4; ++i) a[i] = *(const bf16x8*)(Ab + (long)(16*i+lr)*K + k0);
    #pragma unroll
    for (int j = 0; j < 4; ++j) b[j] = *(const bf16x8*)(Wb + (long)(16*j+lr)*K + k0);
    #pragma unroll
    for (int i = 0; i < 4; ++i)
      #pragma unroll
      for (int j = 0; j < 4; ++j)
        acc[i][j] = __builtin_amdgcn_mfma_f32_16x16x32_bf16(a[i], b[j], acc[i][j], 0, 0, 0);
  }
  double ls = 0.0;
  #pragma unroll
  for (int j = 0; j < 4; ++j){
    const int col = col0 + 16*j + lr;
    const float bv = bias[col];
    #pragma unroll
    for (int i = 0; i < 4; ++i){
      #pragma unroll
      for (int q = 0; q < 4; ++q){
        const int row = row0 + 16*i + (lane>>4)*4 + q;
        const float d = tgt[(long)row*N + col] - (acc[i][j][q] + bv);
        ls += 0.5 * (double)d * (double)d;
      }
    }
  }
  ls = wave_sum_d(ls);
  if (lane == 0) atomicAdd(accp, ls);
}

// reward head over one 8192-row chunk.
__global__ void __launch_bounds__(512) rp_loss_b(const u16* __restrict__ h2,
                                                 const float* __restrict__ W2,
                                                 const float* __restrict__ b2,
                                                 const float* __restrict__ reward,
                                                 double* accp)
{
  const int tid = threadIdx.x;
  const int lane = tid & 63;
  const int wid = blockIdx.x*8 + (tid >> 6);
  double ls = 0.0;
  for (int row = wid; row < 8192; row += 2048) {
    const uint4 hv = *(const uint4*)(h2 + (long)row*FEAT_ + lane*8);
    const float4 w0 = ld4(W2 + lane*8);
    const float4 w1 = ld4(W2 + lane*8 + 4);
    float part = blo(hv.x)*w0.x + bhi(hv.x)*w0.y + blo(hv.y)*w0.z + bhi(hv.y)*w0.w
               + blo(hv.z)*w1.x + bhi(hv.z)*w1.y + blo(hv.w)*w1.z + bhi(hv.w)*w1.w;
    #pragma unroll
    for (int o = 32; o > 0; o >>= 1) part += __shfl_down(part, o, 64);
    if (lane == 0) {
      const float mu = part + b2[0];
      const float d = reward[row] - mu;
      ls += 0.5 * (double)d * (double)d;
    }
  }
  if (lane == 0) atomicAdd(accp, ls);
}

__global__ void final_k(const double* acc, float* out)
{
  const double tot = (acc[0] + acc[1] + acc[2]) / (double)(T_STEPS * B_)
                   + 512.0 * LOG2PI_ + 0.5 * LOG2PI_;
  out[0] = (float)tot;
}

extern "C" void kernel_launch(void* const* d_in, const int* in_sizes, int n_in,
                              void* d_out, int out_size, void* d_ws, size_t ws_size,
                              hipStream_t stream) {
  const float* emb    = (const float*)d_in[0];
  const float* action = (const float*)d_in[1];
  const float* reward = (const float*)d_in[2];
  const float* eps    = (const float*)d_in[3];
  const float* Wih  = (const float*)d_in[4];  const float* bih  = (const float*)d_in[5];
  const float* Whh  = (const float*)d_in[6];  const float* bhh  = (const float*)d_in[7];
  const float* stW0 = (const float*)d_in[8];  const float* stb0 = (const float*)d_in[9];
  const float* stW1 = (const float*)d_in[10]; const float* stb1 = (const float*)d_in[11];
  const float* stW2 = (const float*)d_in[12]; const float* stb2 = (const float*)d_in[13];
  const float* epW0 = (const float*)d_in[14]; const float* epb0 = (const float*)d_in[15];
  const float* epW1 = (const float*)d_in[16]; const float* epb1 = (const float*)d_in[17];
  const float* epW2 = (const float*)d_in[18]; const float* epb2 = (const float*)d_in[19];
  const float* rpW0 = (const float*)d_in[20]; const float* rpb0 = (const float*)d_in[21];
  const float* rpW1 = (const float*)d_in[22]; const float* rpb1 = (const float*)d_in[23];
  const float* rpW2 = (const float*)d_in[24]; const float* rpb2 = (const float*)d_in[25];

  double* acc = (double*)d_ws;
  // workspace (~55 MiB). eprec (16.8 MB) dead after scan; prior chunk bufs
  // (pembb 8.4 + h1b 4.2 + h2b 4.2) and ep/rp M=8192 bufs (h1c 8.4 + h2c 8.4) alias it.
  u16* states_b = (u16*)((char*)d_ws + 256);               // 16384*576*2
  float* qraw   = (float*)(states_b + (long)16384*STATE_); // 16384*128*4
  u16* eprec    = (u16*)(qraw + (long)16384*128);          // 16384*512*2
  u16* pembb = eprec;                                      // 4096*1024*2 (alias)
  u16* h1b   = pembb + (long)4096*EMB_;                    // 4096*512*2 (alias)
  u16* h2b   = h1b + (long)4096*FEAT_;                     // 4096*512*2 (alias)
  u16* h1c   = eprec;                                      // 8192*512*2 (alias)
  u16* h2c   = h1c + (long)8192*FEAT_;                     // 8192*512*2 (alias)
  float* pr2f = (float*)(eprec + (long)16384*512);         // 4096*128*4
  u16* bw = (u16*)(pr2f + (long)4096*128);
  // bf16 tail weights
  u16* bepW0 = bw;    bw += 294912;
  u16* bepW1 = bw;    bw += 262144;
  u16* bepW2 = bw;    bw += 524288;
  u16* bstW0 = bw;    bw += 786432;
  u16* bstW1 = bw;    bw += 262144;
  u16* bstW2 = bw;    bw += 65536;
  u16* brpW0 = bw;    bw += 294912;
  u16* brpW1 = bw;    bw += 262144;
  // f16 scan weights
  u16* hWhh  = bw;    bw += 786432;
  u16* hWih  = bw;    bw += 147456;
  u16* hstW0h= bw;    bw += 262144;
  u16* hstW1 = bw;    bw += 262144;
  u16* hstW2 = bw;    bw += 65536;

  hipMemsetAsync(d_ws, 0, 256, stream);

  convw_k<<<(294912+255)/256, 256, 0, stream>>>(epW0, bepW0, 294912);
  convw_k<<<(262144+255)/256, 256, 0, stream>>>(epW1, bepW1, 262144);
  convw_k<<<(524288+255)/256, 256, 0, stream>>>(epW2, bepW2, 524288);
  convw_k<<<(786432+255)/256, 256, 0, stream>>>(stW0, bstW0, 786432);
  convw_k<<<(262144+255)/256, 256, 0, stream>>>(stW1, bstW1, 262144);
  convw_k<<<(65536+255)/256,  256, 0, stream>>>(stW2, bstW2, 65536);
  convw_k<<<(294912+255)/256, 256, 0, stream>>>(rpW0, brpW0, 294912);
  convw_k<<<(262144+255)/256, 256, 0, stream>>>(rpW1, brpW1, 262144);
  convh_k<<<(786432+255)/256, 256, 0, stream>>>(Whh,  hWhh,  786432);
  convhih_k<<<(147456+255)/256, 256, 0, stream>>>(Wih, hWih);
  convh_sub_k<<<(262144+255)/256, 256, 0, stream>>>(stW0, hstW0h);
  convh_k<<<(262144+255)/256, 256, 0, stream>>>(stW1, hstW1, 262144);
  convh_k<<<(65536+255)/256,  256, 0, stream>>>(stW2, hstW2, 65536);

  // epre = emb_prev @ stW0[:,512:]^T (bf16), all 16384 rows — before the scan
  gemm_epre_k<<<128*4, 256, 0, stream>>>(emb, bstW0, eprec);

  Params p;
  p.emb = emb; p.action = action; p.reward = reward; p.eps = eps;
  p.bih = bih; p.bhh = bhh;
  p.stb0 = stb0; p.stb1 = stb1; p.stb2 = stb2;
  p.epb0 = epb0; p.epb1 = epb1; p.epb2 = epb2;
  p.hWih = hWih; p.hWhh = hWhh;
  p.hstW0h = hstW0h; p.hstW1 = hstW1; p.hstW2 = hstW2;
  p.eprec = eprec;
  p.states = states_b;
  p.qraw = qraw;
  p.acc = acc;
  p.out = (float*)d_out;

  scan_kernel<<<B_, 1024, 0, stream>>>(p);

  // ---- prior chain + KL (deferred from scan), chunks of 4096 rows ----
  for (int ch = 0; ch < 4; ++ch) {
    const u16* S    = states_b + (long)ch*4096*STATE_;
    const u16* Sprev= states_b + ((long)ch*4096 - 256)*STATE_;   // never deref'd when zlo masks
    const int zlo = (ch == 0) ? 256 : 0;
    gemm_h_k<<<32*4, 256, 0, stream>>>(Sprev, bepW0, epb0, h1b, 4, STATE_, 1, zlo);   // pe0
    gemm_h_k<<<32*4, 256, 0, stream>>>(h1b,   bepW1, epb1, h2b, 4, FEAT_, 1, 0);      // pe1
    gemm_h_k<<<32*8, 256, 0, stream>>>(h2b,   bepW2, epb2, pembb, 8, FEAT_, 0, 0);    // pemb
    gemm_cat_k<<<32*4, 256, 0, stream>>>(S, pembb, bstW0, stb0, h1b);                 // pr0
    gemm_h_k<<<32*4, 256, 0, stream>>>(h1b,   bstW1, stb1, h2b, 4, FEAT_, 1, 0);      // pr1
    gemm_raw_k<<<32, 256, 0, stream>>>(h2b, bstW2, stb2, pr2f);                        // pr2
    kl_k<<<512, 512, 0, stream>>>(qraw + (long)ch*4096*128, pr2f, acc);
  }
  // ---- ep chain: states -> h1 -> h2 -> emb loss (M=8192 chunks) ----
  for (int ch = 0; ch < 2; ++ch) {
    const u16* S = states_b + (long)ch*8192*STATE_;
    gemm_h_k<<<64*4, 256, 0, stream>>>(S,   bepW0, epb0, h1c, 4, STATE_, 1, 0);
    gemm_h_k<<<64*4, 256, 0, stream>>>(h1c, bepW1, epb1, h2c, 4, FEAT_, 1, 0);
    gemm_loss_k<<<64*8, 256, 0, stream>>>(h2c, bepW2, epb2, emb + (long)ch*8192*EMB_, 8, FEAT_, acc + 1);
  }
  // ---- rp chain (M=8192 chunks) ----
  for (int ch = 0; ch < 2; ++ch) {
    const u16* S = states_b + (long)ch*8192*STATE_;
    gemm_h_k<<<64*4, 256, 0, stream>>>(S,   brpW0, rpb0, h1c, 4, STATE_, 1, 0);
    gemm_h_k<<<64*4, 256, 0, stream>>>(h1c, brpW1, rpb1, h2c, 4, FEAT_, 1, 0);
    rp_loss_b<<<256, 512, 0, stream>>>(h2c, rpW2, rpb2, reward + (long)ch*8192, acc + 2);
  }
  final_k<<<1, 1, 0, stream>>>(acc, p.out);
}

// Round 9
// 5265.175 us; speedup vs baseline: 1.4791x; 1.4791x over previous
//
#include <hip/hip_runtime.h>
#include <math.h>

typedef unsigned short u16;
typedef __attribute__((ext_vector_type(8))) short bf16x8;
typedef __attribute__((ext_vector_type(4))) float f32x4;
typedef __attribute__((ext_vector_type(2))) _Float16 f16x2;

#define T_STEPS 64
#define B_      256
#define EMB_    1024
#define ACT_    6
#define STOCH_  64
#define HID_    512
#define FEAT_   512
#define STATE_  576
#define G3      1536
#define LOG2PI_ 1.8378770664093453

struct Params {
  const float *emb,*action,*reward,*eps;
  const float *bih,*bhh,*stb0,*stb1,*stb2,*epb0,*epb1,*epb2;
  const u16 *hWih,*hWhh,*hstW0h,*hstW1,*hstW2;   // f16 scan weights, stream-packed
  const u16 *eprec;       // bf16 [T*B][512]: precomputed emb_prev @ stW0[:,512:]^T
  u16 *states;            // bf16 [T*B][STATE_]
  float *qraw;            // [T*B][128]: qmu(64) | qstd(64, post-softplus)
  double *acc;            // [0]=kl [1]=emb [2]=reward
  float *out;
};

__device__ __forceinline__ float4 ld4(const float* p){ return *(const float4*)p; }
__device__ __forceinline__ float elu_f(float x){ return x > 0.f ? x : expm1f(x); }
__device__ __forceinline__ float sigmoid_f(float x){ return 1.f/(1.f+expf(-x)); }
__device__ __forceinline__ float softplus_f(float x){ return x > 20.f ? x : log1pf(expf(x)); }
__device__ __forceinline__ float blo(unsigned u){ return __uint_as_float(u << 16); }
__device__ __forceinline__ float bhi(unsigned u){ return __uint_as_float(u & 0xFFFF0000u); }
__device__ __forceinline__ float bf2f(u16 v){ return __uint_as_float((unsigned)v << 16); }
__device__ __forceinline__ u16 f2bf(float x){     // fp32 -> bf16 RNE
  const unsigned u = __float_as_uint(x);
  return (u16)((u + 0x7FFFu + ((u>>16)&1u)) >> 16);
}
__device__ __forceinline__ u16 f2h(float x){ _Float16 h = (_Float16)x; union{_Float16 h; u16 u;} c; c.h = h; return c.u; }
__device__ __forceinline__ float h2f(u16 v){ union{u16 u; _Float16 h;} c; c.u = v; return (float)c.h; }
__device__ __forceinline__ f16x2 asf2(unsigned u){ union{unsigned u; f16x2 v;} c; c.u = u; return c.v; }
__device__ __forceinline__ float qred(float a){   // reduce over 4-lane cluster
  a += __shfl_xor(a, 1, 64);
  a += __shfl_xor(a, 2, 64);
  return a;
}
__device__ __forceinline__ double wave_sum(double v){
  #pragma unroll
  for (int o = 32; o > 0; o >>= 1) v += __shfl_down(v, o, 64);
  return v;
}

// ---------------- weight converters ----------------
__global__ void convw_k(const float* __restrict__ s, u16* __restrict__ d, int n){
  const int i = blockIdx.x*256 + threadIdx.x;
  if (i < n){
    const unsigned u = __float_as_uint(s[i]);
    d[i] = (u16)((u + 0x7FFFu + ((u>>16)&1u)) >> 16);
  }
}
// Stream-packed f16 repack (R14): src fp32 [N][SK] (first K cols), packed row
// p = (n % RS)*(N/RS) + n/RS  ->  a cluster's NS streams are CONTIGUOUS rows.
// (R13's s*RS row stride = 256KB = L2 set-alias thrash: FETCH 23MB -> 7.4GB.)
__global__ void convhrep_k(const float* __restrict__ s, u16* __restrict__ d,
                           int N, int SK, int K, int RS){
  const int i = blockIdx.x*256 + threadIdx.x;   // < N*K
  if (i < (long)N*K){
    const int n = i / K, k = i - n*K;
    const int NS = N / RS;
    const int pr = (n % RS)*NS + n/RS;
    d[(long)pr*K + k] = f2h(s[(long)n*SK + k]);
  }
}
// Wih [1536][70] -> packed+padded [1536][96] f16 (RS=256, NS=6)
__global__ void convhrep_ih_k(const float* __restrict__ s, u16* __restrict__ d){
  const int i = blockIdx.x*256 + threadIdx.x;   // < 1536*96
  const int n = i/96, k = i%96;
  const int pr = (n % 256)*6 + n/256;
  d[(long)pr*96 + k] = (k < 70) ? f2h(s[n*70 + k]) : (u16)0;
}

// ---------------- packed multi-stream f16 GEMV core (R14) ----------------
// NS streams = NS contiguous packed rows starting at cluster base c*NS.
// Stream s at byte offset s*K*2 from base -> compiler folds into load imm offsets.
// y[s] corresponds to ORIGINAL row c + s*RS.
template<int NS, int K>
__device__ __forceinline__ void gemvP(const u16* __restrict__ W, const u16* __restrict__ x,
                                      int c, int l, float* y){
  const u16* xr = x + l*8;
  const u16* wb = W + (long)c*NS*K + l*8;
  float acc[NS];
  #pragma unroll
  for (int s = 0; s < NS; ++s) acc[s] = 0.f;
  #pragma unroll
  for (int j = 0; j < K/32; ++j){
    const uint4 xv = *(const uint4*)(xr + 32*j);
    #pragma unroll
    for (int s = 0; s < NS; ++s){
      const uint4 a = *(const uint4*)(wb + s*K + 32*j);
      acc[s] = __builtin_amdgcn_fdot2(asf2(a.x), asf2(xv.x), acc[s], false);
      acc[s] = __builtin_amdgcn_fdot2(asf2(a.y), asf2(xv.y), acc[s], false);
      acc[s] = __builtin_amdgcn_fdot2(asf2(a.z), asf2(xv.z), acc[s], false);
      acc[s] = __builtin_amdgcn_fdot2(asf2(a.w), asf2(xv.w), acc[s], false);
    }
  }
  #pragma unroll
  for (int s = 0; s < NS; ++s) y[s] = qred(acc[s]);
}

// ---------------- scan kernel: 1024 thr, merged gh+st0 phase, packed streams -------
// R13 structure (merged fat phase, 6 barriers) + R14 stream-packed weights.
// gh_next = Whh@h_t computed with st0's h-head (both read h_t); gh parked in LDS
// for step t+1 (t=0 seeded gh=bhh). a_{t+1} prefetch folded into sample phase.
__global__ void __launch_bounds__(1024) scan_kernel(Params p)
{
  const int tid = threadIdx.x;
  const int r = blockIdx.x;
  const int c = tid >> 2, l = tid & 3;   // 256 clusters of 4 lanes

  __shared__ __align__(16) u16 hsh[512];       // f16 h
  __shared__ __align__(16) u16 sah[96];        // f16 [s(64) | a(6) | 0-pad]
  __shared__ __align__(16) float gi[G3], gh[G3];
  __shared__ __align__(16) u16 po0h[512], po1h[512];   // f16
  __shared__ __align__(16) float po2[128];

  if (tid < 512) hsh[tid] = 0;
  if (tid < 96)  sah[tid] = 0;
  if (tid < 6)   sah[64 + tid] = f2h(p.action[((long)0*B_ + r)*ACT_ + tid]);
  for (int i = tid; i < G3; i += 1024) gh[i] = p.bhh[i];   // gh(0) = Whh@0 + bhh
  __syncthreads();

  for (int t = 0; t < T_STEPS; ++t){
    // ---- P1: gi = Wih@[s_{t-1}|a_t] (6 packed streams, K=96) ----
    {
      float y[6];
      gemvP<6, 96>(p.hWih, sah, c, l, y);
      if (l == 0){
        #pragma unroll
        for (int s = 0; s < 6; ++s){
          const int n = c + s*256;
          gi[n] = y[s] + p.bih[n];
        }
      }
    }
    __syncthreads();
    // ---- GRU combine -> h_t (gh from previous iteration's P2; biases included) ----
    if (tid < 512){
      const int j = tid;
      const float ir = gi[j], iz = gi[512+j], in_ = gi[1024+j];
      const float hr = gh[j], hz = gh[512+j], hn  = gh[1024+j];
      const float rr = sigmoid_f(ir + hr);
      const float z  = sigmoid_f(iz + hz);
      const float nn = tanhf(in_ + rr*hn);
      const float hv = (1.f - z)*nn + z*h2f(hsh[j]);
      hsh[j] = f2h(hv);
      p.states[((long)t*B_ + r)*STATE_ + j] = f2bf(hv);
    }
    __syncthreads();
    // ---- P2 (fat phase, 8 packed streams): st0 h-head + gh_next = Whh@h_t ----
    {
      float y[2];
      gemvP<2, 512>(p.hstW0h, hsh, c, l, y);
      if (l == 0){
        const u16* ep = p.eprec + ((long)t*B_ + r)*512;
        #pragma unroll
        for (int s = 0; s < 2; ++s){
          const int n = c + s*256;
          po0h[n] = f2h(elu_f(y[s] + p.stb0[n] + bf2f(ep[n])));
        }
      }
    }
    {
      float y[6];
      gemvP<6, 512>(p.hWhh, hsh, c, l, y);
      if (l == 0){
        #pragma unroll
        for (int s = 0; s < 6; ++s){
          const int n = c + s*256;
          gh[n] = y[s] + p.bhh[n];
        }
      }
    }
    __syncthreads();
    // ---- st1 posterior (2 packed streams) ----
    {
      float y[2];
      gemvP<2, 512>(p.hstW1, po0h, c, l, y);
      if (l == 0){
        #pragma unroll
        for (int s = 0; s < 2; ++s){
          const int n = c + s*256;
          po1h[n] = f2h(elu_f(y[s] + p.stb1[n]));
        }
      }
    }
    __syncthreads();
    // ---- st2 posterior (clusters 0..63; RS=64, NS=2 packed) ----
    if (c < 64){
      float y[2];
      gemvP<2, 512>(p.hstW2, po1h, c, l, y);
      if (l == 0){
        po2[c]      = y[0] + p.stb2[c];
        po2[c + 64] = y[1] + p.stb2[c + 64];
      }
    }
    __syncthreads();
    // ---- sample s_t + a_{t+1} prefetch ----
    if (tid < 64){
      const int j = tid;
      const float qmu = po2[j],  qsr = po2[64+j];
      const float qstd = softplus_f(qsr) + 1e-4f;
      const float sv = qmu + qstd * p.eps[((long)t*B_ + r)*STOCH_ + j];
      sah[j] = f2h(sv);
      p.states[((long)t*B_ + r)*STATE_ + 512 + j] = f2bf(sv);
      p.qraw[((long)t*B_ + r)*128 + j]      = qmu;
      p.qraw[((long)t*B_ + r)*128 + 64 + j] = qstd;
    } else if (tid < 70 && t + 1 < T_STEPS){
      sah[tid] = f2h(p.action[((long)(t+1)*B_ + r)*ACT_ + (tid - 64)]);
    }
    __syncthreads();
  }
}

// ---------------- epre GEMM: emb_prev (fp32, in-reg cvt) @ stW0[:,512:]^T -> bf16 ----
__global__ void __launch_bounds__(256) gemm_epre_k(const float* __restrict__ E,
                                                   const u16* __restrict__ W,   // bstW0 full
                                                   u16* __restrict__ Y)
{
  const int NT = 4;
  const int tid = threadIdx.x;
  const int wave = tid >> 6, lane = tid & 63;
  const int bm = blockIdx.x / NT, bn = blockIdx.x % NT;
  const int row0 = bm*128 + ((wave>>1)<<6);
  const int col0 = bn*128 + ((wave&1)<<6);
  const int lr = lane & 15, lk = (lane >> 4) * 8;
  f32x4 acc[4][4] = {};
  for (int k0 = 0; k0 < EMB_; k0 += 32){
    bf16x8 a[4], b[4];
    #pragma unroll
    for (int i = 0; i < 4; ++i){
      const int row = row0 + 16*i + lr;
      const int arow = row - (row >= B_ ? B_ : 0);   // emb_prev shift (128-blocks never straddle)
      const float* src = E + (long)arow*EMB_ + k0 + lk;
      const float4 f0 = ld4(src), f1 = ld4(src + 4);
      bf16x8 v;
      v[0] = (short)f2bf(f0.x); v[1] = (short)f2bf(f0.y);
      v[2] = (short)f2bf(f0.z); v[3] = (short)f2bf(f0.w);
      v[4] = (short)f2bf(f1.x); v[5] = (short)f2bf(f1.y);
      v[6] = (short)f2bf(f1.z); v[7] = (short)f2bf(f1.w);
      a[i] = v;
    }
    #pragma unroll
    for (int j = 0; j < 4; ++j)
      b[j] = *(const bf16x8*)(W + (long)(col0+16*j+lr)*G3 + 512 + k0 + lk);
    #pragma unroll
    for (int i = 0; i < 4; ++i)
      #pragma unroll
      for (int j = 0; j < 4; ++j)
        acc[i][j] = __builtin_amdgcn_mfma_f32_16x16x32_bf16(a[i], b[j], acc[i][j], 0, 0, 0);
  }
  #pragma unroll
  for (int j = 0; j < 4; ++j){
    const int col = col0 + 16*j + lr;
    #pragma unroll
    for (int i = 0; i < 4; ++i)
      #pragma unroll
      for (int q = 0; q < 4; ++q){
        const int row = row0 + 16*i + (lane>>4)*4 + q;
        Y[(long)row*512 + col] = f2bf(acc[i][j][q]);
      }
  }
}

// ---------------- MFMA bf16 tail GEMMs (R10-proven, byte-identical) -----------------

__global__ void __launch_bounds__(256) gemm_h_k(const u16* __restrict__ A,
                                                const u16* __restrict__ W,
                                                const float* __restrict__ bias,
                                                u16* __restrict__ Y,
                                                int NT, int K, int act, int zlo)
{
  const int tid = threadIdx.x;
  const int wave = tid >> 6, lane = tid & 63;
  const int bm = blockIdx.x / NT, bn = blockIdx.x % NT;
  const int row0 = bm*128 + ((wave>>1)<<6);
  const int col0 = bn*128 + ((wave&1)<<6);
  const int lr = lane & 15, lk = (lane >> 4) * 8;
  const int N = NT << 7;
  f32x4 acc[4][4] = {};
  const u16* Ab = A + (long)row0*K + lk;
  const u16* Wb = W + (long)col0*K + lk;
  const bf16x8 zf = {};
  for (int k0 = 0; k0 < K; k0 += 32){
    bf16x8 a[4], b[4];
    #pragma unroll
    for (int i = 0; i < 4; ++i)
      a[i] = (row0 + 16*i >= zlo) ? *(const bf16x8*)(Ab + (long)(16*i+lr)*K + k0) : zf;
    #pragma unroll
    for (int j = 0; j < 4; ++j) b[j] = *(const bf16x8*)(Wb + (long)(16*j+lr)*K + k0);
    #pragma unroll
    for (int i = 0; i < 4; ++i)
      #pragma unroll
      for (int j = 0; j < 4; ++j)
        acc[i][j] = __builtin_amdgcn_mfma_f32_16x16x32_bf16(a[i], b[j], acc[i][j], 0, 0, 0);
  }
  #pragma unroll
  for (int j = 0; j < 4; ++j){
    const int col = col0 + 16*j + lr;
    const float bv = bias[col];
    #pragma unroll
    for (int i = 0; i < 4; ++i){
      #pragma unroll
      for (int q = 0; q < 4; ++q){
        const int row = row0 + 16*i + (lane>>4)*4 + q;
        float v = acc[i][j][q] + bv;
        if (act) v = elu_f(v);
        Y[(long)row*N + col] = f2bf(v);
      }
    }
  }
}

// st0 prior: A = [states.h (ld 576, k<512) | pemb (ld 1024, k>=512)], W [512][1536], elu out
__global__ void __launch_bounds__(256) gemm_cat_k(const u16* __restrict__ A1,
                                                  const u16* __restrict__ A2,
                                                  const u16* __restrict__ W,
                                                  const float* __restrict__ bias,
                                                  u16* __restrict__ Y)
{
  const int NT = 4;
  const int tid = threadIdx.x;
  const int wave = tid >> 6, lane = tid & 63;
  const int bm = blockIdx.x / NT, bn = blockIdx.x % NT;
  const int row0 = bm*128 + ((wave>>1)<<6);
  const int col0 = bn*128 + ((wave&1)<<6);
  const int lr = lane & 15, lk = (lane >> 4) * 8;
  f32x4 acc[4][4] = {};
  for (int k0 = 0; k0 < G3; k0 += 32){
    bf16x8 a[4], b[4];
    #pragma unroll
    for (int i = 0; i < 4; ++i){
      const long row = row0 + 16*i + lr;
      a[i] = (k0 < 512) ? *(const bf16x8*)(A1 + row*STATE_ + k0 + lk)
                        : *(const bf16x8*)(A2 + row*EMB_ + (k0-512) + lk);
    }
    #pragma unroll
    for (int j = 0; j < 4; ++j)
      b[j] = *(const bf16x8*)(W + (long)(col0+16*j+lr)*G3 + k0 + lk);
    #pragma unroll
    for (int i = 0; i < 4; ++i)
      #pragma unroll
      for (int j = 0; j < 4; ++j)
        acc[i][j] = __builtin_amdgcn_mfma_f32_16x16x32_bf16(a[i], b[j], acc[i][j], 0, 0, 0);
  }
  #pragma unroll
  for (int j = 0; j < 4; ++j){
    const int col = col0 + 16*j + lr;
    const float bv = bias[col];
    #pragma unroll
    for (int i = 0; i < 4; ++i){
      #pragma unroll
      for (int q = 0; q < 4; ++q){
        const int row = row0 + 16*i + (lane>>4)*4 + q;
        Y[(long)row*FEAT_ + col] = f2bf(elu_f(acc[i][j][q] + bv));
      }
    }
  }
}

// st2 prior: N=128, K=512, raw f32 out (+bias, no act). grid = M/128 blocks.
__global__ void __launch_bounds__(256) gemm_raw_k(const u16* __restrict__ A,
                                                  const u16* __restrict__ W,
                                                  const float* __restrict__ bias,
                                                  float* __restrict__ Y)
{
  const int tid = threadIdx.x;
  const int wave = tid >> 6, lane = tid & 63;
  const int row0 = blockIdx.x*128 + ((wave>>1)<<6);
  const int col0 = (wave&1)<<6;
  const int lr = lane & 15, lk = (lane >> 4) * 8;
  f32x4 acc[4][4] = {};
  const u16* Ab = A + (long)row0*FEAT_ + lk;
  const u16* Wb = W + (long)col0*FEAT_ + lk;
  for (int k0 = 0; k0 < FEAT_; k0 += 32){
    bf16x8 a[4], b[4];
    #pragma unroll
    for (int i = 0; i < 4; ++i) a[i] = *(const bf16x8*)(Ab + (long)(16*i+lr)*FEAT_ + k0);
    #pragma unroll
    for (int j = 0; j < 4; ++j) b[j] = *(const bf16x8*)(Wb + (long)(16*j+lr)*FEAT_ + k0);
    #pragma unroll
    for (int i = 0; i < 4; ++i)
      #pragma unroll
      for (int j = 0; j < 4; ++j)
        acc[i][j] = __builtin_amdgcn_mfma_f32_16x16x32_bf16(a[i], b[j], acc[i][j], 0, 0, 0);
  }
  #pragma unroll
  for (int j = 0; j < 4; ++j){
    const int col = col0 + 16*j + lr;
    const float bv = bias[col];
    #pragma unroll
    for (int i = 0; i < 4; ++i){
      #pragma unroll
      for (int q = 0; q < 4; ++q){
        const int row = row0 + 16*i + (lane>>4)*4 + q;
        Y[(long)row*128 + col] = acc[i][j][q] + bv;
      }
    }
  }
}

// KL over one 4096-row chunk: q = stored qmu/qstd, pr = prior raw (pmu, psr).
__global__ void __launch_bounds__(512) kl_k(const float* __restrict__ q,
                                            const float* __restrict__ pr,
                                            double* accp)
{
  const int idx = blockIdx.x*512 + threadIdx.x;   // < 4096*64
  const int row = idx >> 6, j = idx & 63;
  const float qmu = q[row*128 + j], qstd = q[row*128 + 64 + j];
  const float pmu = pr[row*128 + j], psr = pr[row*128 + 64 + j];
  const float pstd = softplus_f(psr) + 1e-4f;
  const float dm = qmu - pmu;
  double v = (double)(logf(pstd/qstd) + (qstd*qstd + dm*dm)/(2.f*pstd*pstd) - 0.5f);
  v = wave_sum(v);
  if ((threadIdx.x & 63) == 0) atomicAdd(accp, v);
}

__device__ __forceinline__ double wave_sum_d(double v){
  #pragma unroll
  for (int o = 32; o > 0; o >>= 1) v += __shfl_down(v, o, 64);
  return v;
}

__global__ void __launch_bounds__(256) gemm_loss_k(const u16* __restrict__ A,
                                                   const u16* __restrict__ W,
                                                   const float* __restrict__ bias,
                                                   const float* __restrict__ tgt,
                                                   int NT, int K, double* accp)
{
  const int tid = threadIdx.x;
  const int wave = tid >> 6, lane = tid & 63;
  const int bm = blockIdx.x / NT, bn = blockIdx.x % NT;
  const int row0 = bm*128 + ((wave>>1)<<6);
  const int col0 = bn*128 + ((wave&1)<<6);
  const int lr = lane & 15, lk = (lane >> 4) * 8;
  const int N = NT << 7;
  f32x4 acc[4][4] = {};
  const u16* Ab = A + (long)row0*K + lk;
  const u16* Wb = W + (long)col0*K + lk;
  for (int k0 = 0; k0 < K; k0 += 32){
    bf16x8 a[4], b[4];
    #pragma unroll
    for (int i = 0; i < 4; ++i) a[i] = *(const bf16x8*)(Ab + (long)(16*i+lr)*K + k0);
    #pragma unroll
    for (int j = 0; j < 4; ++j) b[j] = *(const bf16x8*)(Wb + (long)(16*j+lr)*K + k0);
    #pragma unroll
    for (int i = 0; i < 4; ++i)
      #pragma unroll
      for (int j = 0; j < 4; ++j)
        acc[i][j] = __builtin_amdgcn_mfma_f32_16x16x32_bf16(a[i], b[j], acc[i][j], 0, 0, 0);
  }
  double ls = 0.0;
  #pragma unroll
  for (int j = 0; j < 4; ++j){
    const int col = col0 + 16*j + lr;
    const float bv = bias[col];
    #pragma unroll
    for (int i = 0; i < 4; ++i){
      #pragma unroll
      for (int q = 0; q < 4; ++q){
        const int row = row0 + 16*i + (lane>>4)*4 + q;
        const float d = tgt[(long)row*N + col] - (acc[i][j][q] + bv);
        ls += 0.5 * (double)d * (double)d;
      }
    }
  }
  ls = wave_sum_d(ls);
  if (lane == 0) atomicAdd(accp, ls);
}

// reward head over one 8192-row chunk.
__global__ void __launch_bounds__(512) rp_loss_b(const u16* __restrict__ h2,
                                                 const float* __restrict__ W2,
                                                 const float* __restrict__ b2,
                                                 const float* __restrict__ reward,
                                                 double* accp)
{
  const int tid = threadIdx.x;
  const int lane = tid & 63;
  const int wid = blockIdx.x*8 + (tid >> 6);
  double ls = 0.0;
  for (int row = wid; row < 8192; row += 2048) {
    const uint4 hv = *(const uint4*)(h2 + (long)row*FEAT_ + lane*8);
    const float4 w0 = ld4(W2 + lane*8);
    const float4 w1 = ld4(W2 + lane*8 + 4);
    float part = blo(hv.x)*w0.x + bhi(hv.x)*w0.y + blo(hv.y)*w0.z + bhi(hv.y)*w0.w
               + blo(hv.z)*w1.x + bhi(hv.z)*w1.y + blo(hv.w)*w1.z + bhi(hv.w)*w1.w;
    #pragma unroll
    for (int o = 32; o > 0; o >>= 1) part += __shfl_down(part, o, 64);
    if (lane == 0) {
      const float mu = part + b2[0];
      const float d = reward[row] - mu;
      ls += 0.5 * (double)d * (double)d;
    }
  }
  if (lane == 0) atomicAdd(accp, ls);
}

__global__ void final_k(const double* acc, float* out)
{
  const double tot = (acc[0] + acc[1] + acc[2]) / (double)(T_STEPS * B_)
                   + 512.0 * LOG2PI_ + 0.5 * LOG2PI_;
  out[0] = (float)tot;
}

extern "C" void kernel_launch(void* const* d_in, const int* in_sizes, int n_in,
                              void* d_out, int out_size, void* d_ws, size_t ws_size,
                              hipStream_t stream) {
  const float* emb    = (const float*)d_in[0];
  const float* action = (const float*)d_in[1];
  const float* reward = (const float*)d_in[2];
  const float* eps    = (const float*)d_in[3];
  const float* Wih  = (const float*)d_in[4];  const float* bih  = (const float*)d_in[5];
  const float* Whh  = (const float*)d_in[6];  const float* bhh  = (const float*)d_in[7];
  const float* stW0 = (const float*)d_in[8];  const float* stb0 = (const float*)d_in[9];
  const float* stW1 = (const float*)d_in[10]; const float* stb1 = (const float*)d_in[11];
  const float* stW2 = (const float*)d_in[12]; const float* stb2 = (const float*)d_in[13];
  const float* epW0 = (const float*)d_in[14]; const float* epb0 = (const float*)d_in[15];
  const float* epW1 = (const float*)d_in[16]; const float* epb1 = (const float*)d_in[17];
  const float* epW2 = (const float*)d_in[18]; const float* epb2 = (const float*)d_in[19];
  const float* rpW0 = (const float*)d_in[20]; const float* rpb0 = (const float*)d_in[21];
  const float* rpW1 = (const float*)d_in[22]; const float* rpb1 = (const float*)d_in[23];
  const float* rpW2 = (const float*)d_in[24]; const float* rpb2 = (const float*)d_in[25];

  double* acc = (double*)d_ws;
  // workspace (~55 MiB). eprec (16.8 MB) dead after scan; prior chunk bufs
  // (pembb 8.4 + h1b 4.2 + h2b 4.2) and ep/rp M=8192 bufs (h1c 8.4 + h2c 8.4) alias it.
  u16* states_b = (u16*)((char*)d_ws + 256);               // 16384*576*2
  float* qraw   = (float*)(states_b + (long)16384*STATE_); // 16384*128*4
  u16* eprec    = (u16*)(qraw + (long)16384*128);          // 16384*512*2
  u16* pembb = eprec;                                      // 4096*1024*2 (alias)
  u16* h1b   = pembb + (long)4096*EMB_;                    // 4096*512*2 (alias)
  u16* h2b   = h1b + (long)4096*FEAT_;                     // 4096*512*2 (alias)
  u16* h1c   = eprec;                                      // 8192*512*2 (alias)
  u16* h2c   = h1c + (long)8192*FEAT_;                     // 8192*512*2 (alias)
  float* pr2f = (float*)(eprec + (long)16384*512);         // 4096*128*4
  u16* bw = (u16*)(pr2f + (long)4096*128);
  // bf16 tail weights
  u16* bepW0 = bw;    bw += 294912;
  u16* bepW1 = bw;    bw += 262144;
  u16* bepW2 = bw;    bw += 524288;
  u16* bstW0 = bw;    bw += 786432;
  u16* bstW1 = bw;    bw += 262144;
  u16* bstW2 = bw;    bw += 65536;
  u16* brpW0 = bw;    bw += 294912;
  u16* brpW1 = bw;    bw += 262144;
  // f16 scan weights (stream-packed)
  u16* hWhh  = bw;    bw += 786432;
  u16* hWih  = bw;    bw += 147456;
  u16* hstW0h= bw;    bw += 262144;
  u16* hstW1 = bw;    bw += 262144;
  u16* hstW2 = bw;    bw += 65536;

  hipMemsetAsync(d_ws, 0, 256, stream);

  convw_k<<<(294912+255)/256, 256, 0, stream>>>(epW0, bepW0, 294912);
  convw_k<<<(262144+255)/256, 256, 0, stream>>>(epW1, bepW1, 262144);
  convw_k<<<(524288+255)/256, 256, 0, stream>>>(epW2, bepW2, 524288);
  convw_k<<<(786432+255)/256, 256, 0, stream>>>(stW0, bstW0, 786432);
  convw_k<<<(262144+255)/256, 256, 0, stream>>>(stW1, bstW1, 262144);
  convw_k<<<(65536+255)/256,  256, 0, stream>>>(stW2, bstW2, 65536);
  convw_k<<<(294912+255)/256, 256, 0, stream>>>(rpW0, brpW0, 294912);
  convw_k<<<(262144+255)/256, 256, 0, stream>>>(rpW1, brpW1, 262144);
  // stream-packed f16 scan weights
  convhrep_k<<<(786432+255)/256, 256, 0, stream>>>(Whh,  hWhh,  1536, 512, 512, 256);
  convhrep_ih_k<<<(147456+255)/256, 256, 0, stream>>>(Wih, hWih);
  convhrep_k<<<(262144+255)/256, 256, 0, stream>>>(stW0, hstW0h, 512, G3, 512, 256);
  convhrep_k<<<(262144+255)/256, 256, 0, stream>>>(stW1, hstW1, 512, 512, 512, 256);
  convhrep_k<<<(65536+255)/256,  256, 0, stream>>>(stW2, hstW2, 128, 512, 512, 64);

  // epre = emb_prev @ stW0[:,512:]^T (bf16), all 16384 rows — before the scan
  gemm_epre_k<<<128*4, 256, 0, stream>>>(emb, bstW0, eprec);

  Params p;
  p.emb = emb; p.action = action; p.reward = reward; p.eps = eps;
  p.bih = bih; p.bhh = bhh;
  p.stb0 = stb0; p.stb1 = stb1; p.stb2 = stb2;
  p.epb0 = epb0; p.epb1 = epb1; p.epb2 = epb2;
  p.hWih = hWih; p.hWhh = hWhh;
  p.hstW0h = hstW0h; p.hstW1 = hstW1; p.hstW2 = hstW2;
  p.eprec = eprec;
  p.states = states_b;
  p.qraw = qraw;
  p.acc = acc;
  p.out = (float*)d_out;

  scan_kernel<<<B_, 1024, 0, stream>>>(p);

  // ---- prior chain + KL (deferred from scan), chunks of 4096 rows ----
  for (int ch = 0; ch < 4; ++ch) {
    const u16* S    = states_b + (long)ch*4096*STATE_;
    const u16* Sprev= states_b + ((long)ch*4096 - 256)*STATE_;   // never deref'd when zlo masks
    const int zlo = (ch == 0) ? 256 : 0;
    gemm_h_k<<<32*4, 256, 0, stream>>>(Sprev, bepW0, epb0, h1b, 4, STATE_, 1, zlo);   // pe0
    gemm_h_k<<<32*4, 256, 0, stream>>>(h1b,   bepW1, epb1, h2b, 4, FEAT_, 1, 0);      // pe1
    gemm_h_k<<<32*8, 256, 0, stream>>>(h2b,   bepW2, epb2, pembb, 8, FEAT_, 0, 0);    // pemb
    gemm_cat_k<<<32*4, 256, 0, stream>>>(S, pembb, bstW0, stb0, h1b);                 // pr0
    gemm_h_k<<<32*4, 256, 0, stream>>>(h1b,   bstW1, stb1, h2b, 4, FEAT_, 1, 0);      // pr1
    gemm_raw_k<<<32, 256, 0, stream>>>(h2b, bstW2, stb2, pr2f);                        // pr2
    kl_k<<<512, 512, 0, stream>>>(qraw + (long)ch*4096*128, pr2f, acc);
  }
  // ---- ep chain: states -> h1 -> h2 -> emb loss (M=8192 chunks) ----
  for (int ch = 0; ch < 2; ++ch) {
    const u16* S = states_b + (long)ch*8192*STATE_;
    gemm_h_k<<<64*4, 256, 0, stream>>>(S,   bepW0, epb0, h1c, 4, STATE_, 1, 0);
    gemm_h_k<<<64*4, 256, 0, stream>>>(h1c, bepW1, epb1, h2c, 4, FEAT_, 1, 0);
    gemm_loss_k<<<64*8, 256, 0, stream>>>(h2c, bepW2, epb2, emb + (long)ch*8192*EMB_, 8, FEAT_, acc + 1);
  }
  // ---- rp chain (M=8192 chunks) ----
  for (int ch = 0; ch < 2; ++ch) {
    const u16* S = states_b + (long)ch*8192*STATE_;
    gemm_h_k<<<64*4, 256, 0, stream>>>(S,   brpW0, rpb0, h1c, 4, STATE_, 1, 0);
    gemm_h_k<<<64*4, 256, 0, stream>>>(h1c, brpW1, rpb1, h2c, 4, FEAT_, 1, 0);
    rp_loss_b<<<256, 512, 0, stream>>>(h2c, rpW2, rpb2, reward + (long)ch*8192, acc + 2);
  }
  final_k<<<1, 1, 0, stream>>>(acc, p.out);
}

// Round 10
// 4747.441 us; speedup vs baseline: 1.6404x; 1.1091x over previous
//
#include <hip/hip_runtime.h>
#include <math.h>

typedef unsigned short u16;
typedef __attribute__((ext_vector_type(8))) short bf16x8;
typedef __attribute__((ext_vector_type(4))) float f32x4;
typedef __attribute__((ext_vector_type(2))) _Float16 f16x2;

#define T_STEPS 64
#define B_      256
#define EMB_    1024
#define ACT_    6
#define STOCH_  64
#define HID_    512
#define FEAT_   512
#define STATE_  576
#define G3      1536
#define LOG2PI_ 1.8378770664093453

struct Params {
  const float *emb,*action,*reward,*eps;
  const float *bih,*bhh,*stb0,*stb1,*stb2,*epb0,*epb1,*epb2;
  const u16 *hWih,*hWhh,*hstW0h,*hstW1,*hstW2;   // f16 scan weights
  const u16 *eprec;       // bf16 [T*B][512]: precomputed emb_prev @ stW0[:,512:]^T
  u16 *states;            // bf16 [T*B][STATE_]
  float *qraw;            // [T*B][128]: qmu(64) | qstd(64, post-softplus)
  double *acc;            // [0]=kl [1]=emb [2]=reward
  float *out;
};

__device__ __forceinline__ float4 ld4(const float* p){ return *(const float4*)p; }
__device__ __forceinline__ float elu_f(float x){ return x > 0.f ? x : expm1f(x); }
__device__ __forceinline__ float sigmoid_f(float x){ return 1.f/(1.f+expf(-x)); }
__device__ __forceinline__ float softplus_f(float x){ return x > 20.f ? x : log1pf(expf(x)); }
__device__ __forceinline__ float blo(unsigned u){ return __uint_as_float(u << 16); }
__device__ __forceinline__ float bhi(unsigned u){ return __uint_as_float(u & 0xFFFF0000u); }
__device__ __forceinline__ float bf2f(u16 v){ return __uint_as_float((unsigned)v << 16); }
__device__ __forceinline__ u16 f2bf(float x){     // fp32 -> bf16 RNE
  const unsigned u = __float_as_uint(x);
  return (u16)((u + 0x7FFFu + ((u>>16)&1u)) >> 16);
}
__device__ __forceinline__ u16 f2h(float x){ _Float16 h = (_Float16)x; union{_Float16 h; u16 u;} c; c.h = h; return c.u; }
__device__ __forceinline__ float h2f(u16 v){ union{u16 u; _Float16 h;} c; c.u = v; return (float)c.h; }
__device__ __forceinline__ f16x2 asf2(unsigned u){ union{unsigned u; f16x2 v;} c; c.u = u; return c.v; }
__device__ __forceinline__ float qred(float a){   // reduce over 4-lane cluster
  a += __shfl_xor(a, 1, 64);
  a += __shfl_xor(a, 2, 64);
  return a;
}
__device__ __forceinline__ double wave_sum(double v){
  #pragma unroll
  for (int o = 32; o > 0; o >>= 1) v += __shfl_down(v, o, 64);
  return v;
}

// ---------------- weight converters ----------------
__global__ void convw_k(const float* __restrict__ s, u16* __restrict__ d, int n){
  const int i = blockIdx.x*256 + threadIdx.x;
  if (i < n){
    const unsigned u = __float_as_uint(s[i]);
    d[i] = (u16)((u + 0x7FFFu + ((u>>16)&1u)) >> 16);
  }
}
// fp32 -> f16 (RNE)
__global__ void convh_k(const float* __restrict__ s, u16* __restrict__ d, int n){
  const int i = blockIdx.x*256 + threadIdx.x;
  if (i < n) d[i] = f2h(s[i]);
}
// Wih [1536][70] -> padded [1536][96] f16 (zero pad)
__global__ void convhih_k(const float* __restrict__ s, u16* __restrict__ d){
  const int i = blockIdx.x*256 + threadIdx.x;   // < 1536*96
  const int n = i/96, k = i%96;
  d[i] = (k < 70) ? f2h(s[n*70 + k]) : (u16)0;
}
// stW0 h-head: [512][1536] -> packed [512][512] f16 (cols 0..511)
__global__ void convh_sub_k(const float* __restrict__ s, u16* __restrict__ d){
  const int i = blockIdx.x*256 + threadIdx.x;   // < 512*512
  if (i < 512*512){
    const int n = i >> 9, k = i & 511;
    d[i] = f2h(s[(long)n*G3 + k]);
  }
}

// ---------------- scan GEMV core: f16 W & x via v_dot2_f32_f16 (R15) ----------------
// R7 structure/addresses byte-identical; explicit distance-2 prefetch ring so the
// scheduler fills the raised VGPR budget with in-flight loads (R12 at VGPR=64 could
// only keep ~6 loads in flight -> 85% stall). Ring indices are compile-time (rule:
// runtime-indexed arrays spill to scratch; full unroll keeps j&1 static).
template<int K>
__device__ __forceinline__ void gemv2h(const u16* __restrict__ W, const u16* __restrict__ x,
                                       int n0, int n1, int l, float& y0, float& y1){
  constexpr int NJ = K/32;
  const u16* w0 = W + (long)n0*K + l*8;
  const u16* w1 = W + (long)n1*K + l*8;
  const u16* xr = x + l*8;
  float a0=0.f, a1=0.f, b0=0.f, b1=0.f;
  uint4 aq[2], bq[2], xq[2];
  aq[0] = *(const uint4*)(w0); bq[0] = *(const uint4*)(w1); xq[0] = *(const uint4*)(xr);
  if (NJ > 1){
    aq[1] = *(const uint4*)(w0 + 32); bq[1] = *(const uint4*)(w1 + 32); xq[1] = *(const uint4*)(xr + 32);
  }
  #pragma unroll
  for (int j = 0; j < NJ; ++j){
    const uint4 a  = aq[j & 1];
    const uint4 b  = bq[j & 1];
    const uint4 xv = xq[j & 1];
    if (j + 2 < NJ){
      aq[j & 1] = *(const uint4*)(w0 + 32*(j+2));
      bq[j & 1] = *(const uint4*)(w1 + 32*(j+2));
      xq[j & 1] = *(const uint4*)(xr + 32*(j+2));
    }
    a0 = __builtin_amdgcn_fdot2(asf2(a.x), asf2(xv.x), a0, false);
    a1 = __builtin_amdgcn_fdot2(asf2(a.y), asf2(xv.y), a1, false);
    a0 = __builtin_amdgcn_fdot2(asf2(a.z), asf2(xv.z), a0, false);
    a1 = __builtin_amdgcn_fdot2(asf2(a.w), asf2(xv.w), a1, false);
    b0 = __builtin_amdgcn_fdot2(asf2(b.x), asf2(xv.x), b0, false);
    b1 = __builtin_amdgcn_fdot2(asf2(b.y), asf2(xv.y), b1, false);
    b0 = __builtin_amdgcn_fdot2(asf2(b.z), asf2(xv.z), b0, false);
    b1 = __builtin_amdgcn_fdot2(asf2(b.w), asf2(xv.w), b1, false);
  }
  y0 = qred(a0 + a1);
  y1 = qred(b0 + b1);
}

// ---------------- scan kernel: 1024 thr, R7 phases + VGPR-budget raise (R15) -------
// amdgpu_waves_per_eu(4,4): exactly 4 waves/SIMD (= our 1 block/CU grid) -> VGPR
// budget 128 instead of the default 64 (m69 tiers: 16 waves/CU legal at <=128).
// Every 1024-thr variant so far compiled to VGPR=64 -> ~6 loads in flight -> the
// measured 85% stall. Phases/addresses identical to the proven 3120us R12 kernel.
__global__ void __launch_bounds__(1024)
__attribute__((amdgpu_waves_per_eu(4,4)))
scan_kernel(Params p)
{
  const int tid = threadIdx.x;
  const int r = blockIdx.x;
  const int c = tid >> 2, l = tid & 3;   // 256 clusters of 4 lanes

  __shared__ __align__(16) u16 hsh[STATE_];    // f16 [h(512) | s(64)]
  __shared__ __align__(16) u16 sah[96];        // f16 [s(64) | a(6) | 0-pad]
  __shared__ __align__(16) float gi[G3], gh[G3];
  __shared__ __align__(16) u16 po0h[512], po1h[512];   // f16
  __shared__ __align__(16) float po2[128];

  if (tid < STATE_) hsh[tid] = 0;
  __syncthreads();

  for (int t = 0; t < T_STEPS; ++t){
    // ---- prologue: sa = [s_{t-1} | a_t | 0] (f16) ----
    if (tid < 96){
      u16 v = 0;
      if (tid < 64)      v = hsh[512 + tid];
      else if (tid < 70) v = f2h(p.action[((long)t*B_ + r)*ACT_ + (tid - 64)]);
      sah[tid] = v;
    }
    __syncthreads();
    // ---- gh (3p), gi (3p) ----
    #pragma unroll
    for (int ps = 0; ps < 3; ++ps){
      const int n0 = ps*512 + c, n1 = n0 + 256;
      float y0, y1;
      gemv2h<HID_>(p.hWhh, hsh, n0, n1, l, y0, y1);
      if (l == 0){
        gh[n0] = y0 + p.bhh[n0];
        gh[n1] = y1 + p.bhh[n1];
      }
    }
    #pragma unroll
    for (int ps = 0; ps < 3; ++ps){
      const int n0 = ps*512 + c, n1 = n0 + 256;
      float y0, y1;
      gemv2h<96>(p.hWih, sah, n0, n1, l, y0, y1);
      if (l == 0){
        gi[n0] = y0 + p.bih[n0];
        gi[n1] = y1 + p.bih[n1];
      }
    }
    __syncthreads();
    // ---- GRU combine -> h_t ----
    if (tid < 512){
      const int j = tid;
      const float ir = gi[j], iz = gi[512+j], in_ = gi[1024+j];
      const float hr = gh[j], hz = gh[512+j], hn  = gh[1024+j];
      const float rr = sigmoid_f(ir + hr);
      const float z  = sigmoid_f(iz + hz);
      const float nn = tanhf(in_ + rr*hn);
      const float hv = (1.f - z)*nn + z*h2f(hsh[j]);
      hsh[j] = f2h(hv);
      p.states[((long)t*B_ + r)*STATE_ + j] = f2bf(hv);
    }
    __syncthreads();
    // ---- st0 posterior h-head (K=512, packed f16) + precomputed emb-tail ----
    {
      const int n0 = c, n1 = c + 256;
      float y0, y1;
      gemv2h<HID_>(p.hstW0h, hsh, n0, n1, l, y0, y1);
      if (l == 0){
        const u16* ep = p.eprec + ((long)t*B_ + r)*512;
        po0h[n0] = f2h(elu_f(y0 + p.stb0[n0] + bf2f(ep[n0])));
        po0h[n1] = f2h(elu_f(y1 + p.stb0[n1] + bf2f(ep[n1])));
      }
    }
    __syncthreads();
    // ---- st1 posterior ----
    {
      const int n0 = c, n1 = c + 256;
      float y0, y1;
      gemv2h<FEAT_>(p.hstW1, po0h, n0, n1, l, y0, y1);
      if (l == 0){
        po1h[n0] = f2h(elu_f(y0 + p.stb1[n0]));
        po1h[n1] = f2h(elu_f(y1 + p.stb1[n1]));
      }
    }
    __syncthreads();
    // ---- st2 posterior (clusters 0..63) ----
    if (c < 64){
      const int n0 = c, n1 = c + 64;
      float y0, y1;
      gemv2h<FEAT_>(p.hstW2, po1h, n0, n1, l, y0, y1);
      if (l == 0){
        po2[n0] = y0 + p.stb2[n0];
        po2[n1] = y1 + p.stb2[n1];
      }
    }
    __syncthreads();
    // ---- sample s_t, store qmu/qstd ----
    if (tid < 64){
      const int j = tid;
      const float qmu = po2[j],  qsr = po2[64+j];
      const float qstd = softplus_f(qsr) + 1e-4f;
      const float sv = qmu + qstd * p.eps[((long)t*B_ + r)*STOCH_ + j];
      hsh[512 + j] = f2h(sv);
      p.states[((long)t*B_ + r)*STATE_ + 512 + j] = f2bf(sv);
      p.qraw[((long)t*B_ + r)*128 + j]      = qmu;
      p.qraw[((long)t*B_ + r)*128 + 64 + j] = qstd;
    }
    __syncthreads();
  }
}

// ---------------- epre GEMM: emb_prev (fp32, in-reg cvt) @ stW0[:,512:]^T -> bf16 ----
__global__ void __launch_bounds__(256) gemm_epre_k(const float* __restrict__ E,
                                                   const u16* __restrict__ W,   // bstW0 full
                                                   u16* __restrict__ Y)
{
  const int NT = 4;
  const int tid = threadIdx.x;
  const int wave = tid >> 6, lane = tid & 63;
  const int bm = blockIdx.x / NT, bn = blockIdx.x % NT;
  const int row0 = bm*128 + ((wave>>1)<<6);
  const int col0 = bn*128 + ((wave&1)<<6);
  const int lr = lane & 15, lk = (lane >> 4) * 8;
  f32x4 acc[4][4] = {};
  for (int k0 = 0; k0 < EMB_; k0 += 32){
    bf16x8 a[4], b[4];
    #pragma unroll
    for (int i = 0; i < 4; ++i){
      const int row = row0 + 16*i + lr;
      const int arow = row - (row >= B_ ? B_ : 0);   // emb_prev shift (128-blocks never straddle)
      const float* src = E + (long)arow*EMB_ + k0 + lk;
      const float4 f0 = ld4(src), f1 = ld4(src + 4);
      bf16x8 v;
      v[0] = (short)f2bf(f0.x); v[1] = (short)f2bf(f0.y);
      v[2] = (short)f2bf(f0.z); v[3] = (short)f2bf(f0.w);
      v[4] = (short)f2bf(f1.x); v[5] = (short)f2bf(f1.y);
      v[6] = (short)f2bf(f1.z); v[7] = (short)f2bf(f1.w);
      a[i] = v;
    }
    #pragma unroll
    for (int j = 0; j < 4; ++j)
      b[j] = *(const bf16x8*)(W + (long)(col0+16*j+lr)*G3 + 512 + k0 + lk);
    #pragma unroll
    for (int i = 0; i < 4; ++i)
      #pragma unroll
      for (int j = 0; j < 4; ++j)
        acc[i][j] = __builtin_amdgcn_mfma_f32_16x16x32_bf16(a[i], b[j], acc[i][j], 0, 0, 0);
  }
  #pragma unroll
  for (int j = 0; j < 4; ++j){
    const int col = col0 + 16*j + lr;
    #pragma unroll
    for (int i = 0; i < 4; ++i)
      #pragma unroll
      for (int q = 0; q < 4; ++q){
        const int row = row0 + 16*i + (lane>>4)*4 + q;
        Y[(long)row*512 + col] = f2bf(acc[i][j][q]);
      }
  }
}

// ---------------- MFMA bf16 tail GEMMs (R10-proven, byte-identical) -----------------

__global__ void __launch_bounds__(256) gemm_h_k(const u16* __restrict__ A,
                                                const u16* __restrict__ W,
                                                const float* __restrict__ bias,
                                                u16* __restrict__ Y,
                                                int NT, int K, int act, int zlo)
{
  const int tid = threadIdx.x;
  const int wave = tid >> 6, lane = tid & 63;
  const int bm = blockIdx.x / NT, bn = blockIdx.x % NT;
  const int row0 = bm*128 + ((wave>>1)<<6);
  const int col0 = bn*128 + ((wave&1)<<6);
  const int lr = lane & 15, lk = (lane >> 4) * 8;
  const int N = NT << 7;
  f32x4 acc[4][4] = {};
  const u16* Ab = A + (long)row0*K + lk;
  const u16* Wb = W + (long)col0*K + lk;
  const bf16x8 zf = {};
  for (int k0 = 0; k0 < K; k0 += 32){
    bf16x8 a[4], b[4];
    #pragma unroll
    for (int i = 0; i < 4; ++i)
      a[i] = (row0 + 16*i >= zlo) ? *(const bf16x8*)(Ab + (long)(16*i+lr)*K + k0) : zf;
    #pragma unroll
    for (int j = 0; j < 4; ++j) b[j] = *(const bf16x8*)(Wb + (long)(16*j+lr)*K + k0);
    #pragma unroll
    for (int i = 0; i < 4; ++i)
      #pragma unroll
      for (int j = 0; j < 4; ++j)
        acc[i][j] = __builtin_amdgcn_mfma_f32_16x16x32_bf16(a[i], b[j], acc[i][j], 0, 0, 0);
  }
  #pragma unroll
  for (int j = 0; j < 4; ++j){
    const int col = col0 + 16*j + lr;
    const float bv = bias[col];
    #pragma unroll
    for (int i = 0; i < 4; ++i){
      #pragma unroll
      for (int q = 0; q < 4; ++q){
        const int row = row0 + 16*i + (lane>>4)*4 + q;
        float v = acc[i][j][q] + bv;
        if (act) v = elu_f(v);
        Y[(long)row*N + col] = f2bf(v);
      }
    }
  }
}

// st0 prior: A = [states.h (ld 576, k<512) | pemb (ld 1024, k>=512)], W [512][1536], elu out
__global__ void __launch_bounds__(256) gemm_cat_k(const u16* __restrict__ A1,
                                                  const u16* __restrict__ A2,
                                                  const u16* __restrict__ W,
                                                  const float* __restrict__ bias,
                                                  u16* __restrict__ Y)
{
  const int NT = 4;
  const int tid = threadIdx.x;
  const int wave = tid >> 6, lane = tid & 63;
  const int bm = blockIdx.x / NT, bn = blockIdx.x % NT;
  const int row0 = bm*128 + ((wave>>1)<<6);
  const int col0 = bn*128 + ((wave&1)<<6);
  const int lr = lane & 15, lk = (lane >> 4) * 8;
  f32x4 acc[4][4] = {};
  for (int k0 = 0; k0 < G3; k0 += 32){
    bf16x8 a[4], b[4];
    #pragma unroll
    for (int i = 0; i < 4; ++i){
      const long row = row0 + 16*i + lr;
      a[i] = (k0 < 512) ? *(const bf16x8*)(A1 + row*STATE_ + k0 + lk)
                        : *(const bf16x8*)(A2 + row*EMB_ + (k0-512) + lk);
    }
    #pragma unroll
    for (int j = 0; j < 4; ++j)
      b[j] = *(const bf16x8*)(W + (long)(col0+16*j+lr)*G3 + k0 + lk);
    #pragma unroll
    for (int i = 0; i < 4; ++i)
      #pragma unroll
      for (int j = 0; j < 4; ++j)
        acc[i][j] = __builtin_amdgcn_mfma_f32_16x16x32_bf16(a[i], b[j], acc[i][j], 0, 0, 0);
  }
  #pragma unroll
  for (int j = 0; j < 4; ++j){
    const int col = col0 + 16*j + lr;
    const float bv = bias[col];
    #pragma unroll
    for (int i = 0; i < 4; ++i){
      #pragma unroll
      for (int q = 0; q < 4; ++q){
        const int row = row0 + 16*i + (lane>>4)*4 + q;
        Y[(long)row*FEAT_ + col] = f2bf(elu_f(acc[i][j][q] + bv));
      }
    }
  }
}

// st2 prior: N=128, K=512, raw f32 out (+bias, no act). grid = M/128 blocks.
__global__ void __launch_bounds__(256) gemm_raw_k(const u16* __restrict__ A,
                                                  const u16* __restrict__ W,
                                                  const float* __restrict__ bias,
                                                  float* __restrict__ Y)
{
  const int tid = threadIdx.x;
  const int wave = tid >> 6, lane = tid & 63;
  const int row0 = blockIdx.x*128 + ((wave>>1)<<6);
  const int col0 = (wave&1)<<6;
  const int lr = lane & 15, lk = (lane >> 4) * 8;
  f32x4 acc[4][4] = {};
  const u16* Ab = A + (long)row0*FEAT_ + lk;
  const u16* Wb = W + (long)col0*FEAT_ + lk;
  for (int k0 = 0; k0 < FEAT_; k0 += 32){
    bf16x8 a[4], b[4];
    #pragma unroll
    for (int i = 0; i < 4; ++i) a[i] = *(const bf16x8*)(Ab + (long)(16*i+lr)*FEAT_ + k0);
    #pragma unroll
    for (int j = 0; j < 4; ++j) b[j] = *(const bf16x8*)(Wb + (long)(16*j+lr)*FEAT_ + k0);
    #pragma unroll
    for (int i = 0; i < 4; ++i)
      #pragma unroll
      for (int j = 0; j < 4; ++j)
        acc[i][j] = __builtin_amdgcn_mfma_f32_16x16x32_bf16(a[i], b[j], acc[i][j], 0, 0, 0);
  }
  #pragma unroll
  for (int j = 0; j < 4; ++j){
    const int col = col0 + 16*j + lr;
    const float bv = bias[col];
    #pragma unroll
    for (int i = 0; i < 4; ++i){
      #pragma unroll
      for (int q = 0; q < 4; ++q){
        const int row = row0 + 16*i + (lane>>4)*4 + q;
        Y[(long)row*128 + col] = acc[i][j][q] + bv;
      }
    }
  }
}

// KL over one 4096-row chunk: q = stored qmu/qstd, pr = prior raw (pmu, psr).
__global__ void __launch_bounds__(512) kl_k(const float* __restrict__ q,
                                            const float* __restrict__ pr,
                                            double* accp)
{
  const int idx = blockIdx.x*512 + threadIdx.x;   // < 4096*64
  const int row = idx >> 6, j = idx & 63;
  const float qmu = q[row*128 + j], qstd = q[row*128 + 64 + j];
  const float pmu = pr[row*128 + j], psr = pr[row*128 + 64 + j];
  const float pstd = softplus_f(psr) + 1e-4f;
  const float dm = qmu - pmu;
  double v = (double)(logf(pstd/qstd) + (qstd*qstd + dm*dm)/(2.f*pstd*pstd) - 0.5f);
  v = wave_sum(v);
  if ((threadIdx.x & 63) == 0) atomicAdd(accp, v);
}

__device__ __forceinline__ double wave_sum_d(double v){
  #pragma unroll
  for (int o = 32; o > 0; o >>= 1) v += __shfl_down(v, o, 64);
  return v;
}

__global__ void __launch_bounds__(256) gemm_loss_k(const u16* __restrict__ A,
                                                   const u16* __restrict__ W,
                                                   const float* __restrict__ bias,
                                                   const float* __restrict__ tgt,
                                                   int NT, int K, double* accp)
{
  const int tid = threadIdx.x;
  const int wave = tid >> 6, lane = tid & 63;
  const int bm = blockIdx.x / NT, bn = blockIdx.x % NT;
  const int row0 = bm*128 + ((wave>>1)<<6);
  const int col0 = bn*128 + ((wave&1)<<6);
  const int lr = lane & 15, lk = (lane >> 4) * 8;
  const int N = NT << 7;
  f32x4 acc[4][4] = {};
  const u16* Ab = A + (long)row0*K + lk;
  const u16* Wb = W + (long)col0*K + lk;
  for (int k0 = 0; k0 < K; k0 += 32){
    bf16x8 a[4], b[4];
    #pragma unroll
    for (int i = 0; i < 4; ++i) a[i] = *(const bf16x8*)(Ab + (long)(16*i+lr)*K + k0);
    #pragma unroll
    for (int j = 0; j < 4; ++j) b[j] = *(const bf16x8*)(Wb + (long)(16*j+lr)*K + k0);
    #pragma unroll
    for (int i = 0; i < 4; ++i)
      #pragma unroll
      for (int j = 0; j < 4; ++j)
        acc[i][j] = __builtin_amdgcn_mfma_f32_16x16x32_bf16(a[i], b[j], acc[i][j], 0, 0, 0);
  }
  double ls = 0.0;
  #pragma unroll
  for (int j = 0; j < 4; ++j){
    const int col = col0 + 16*j + lr;
    const float bv = bias[col];
    #pragma unroll
    for (int i = 0; i < 4; ++i){
      #pragma unroll
      for (int q = 0; q < 4; ++q){
        const int row = row0 + 16*i + (lane>>4)*4 + q;
        const float d = tgt[(long)row*N + col] - (acc[i][j][q] + bv);
        ls += 0.5 * (double)d * (double)d;
      }
    }
  }
  ls = wave_sum_d(ls);
  if (lane == 0) atomicAdd(accp, ls);
}

// reward head over one 8192-row chunk.
__global__ void __launch_bounds__(512) rp_loss_b(const u16* __restrict__ h2,
                                                 const float* __restrict__ W2,
                                                 const float* __restrict__ b2,
                                                 const float* __restrict__ reward,
                                                 double* accp)
{
  const int tid = threadIdx.x;
  const int lane = tid & 63;
  const int wid = blockIdx.x*8 + (tid >> 6);
  double ls = 0.0;
  for (int row = wid; row < 8192; row += 2048) {
    const uint4 hv = *(const uint4*)(h2 + (long)row*FEAT_ + lane*8);
    const float4 w0 = ld4(W2 + lane*8);
    const float4 w1 = ld4(W2 + lane*8 + 4);
    float part = blo(hv.x)*w0.x + bhi(hv.x)*w0.y + blo(hv.y)*w0.z + bhi(hv.y)*w0.w
               + blo(hv.z)*w1.x + bhi(hv.z)*w1.y + blo(hv.w)*w1.z + bhi(hv.w)*w1.w;
    #pragma unroll
    for (int o = 32; o > 0; o >>= 1) part += __shfl_down(part, o, 64);
    if (lane == 0) {
      const float mu = part + b2[0];
      const float d = reward[row] - mu;
      ls += 0.5 * (double)d * (double)d;
    }
  }
  if (lane == 0) atomicAdd(accp, ls);
}

__global__ void final_k(const double* acc, float* out)
{
  const double tot = (acc[0] + acc[1] + acc[2]) / (double)(T_STEPS * B_)
                   + 512.0 * LOG2PI_ + 0.5 * LOG2PI_;
  out[0] = (float)tot;
}

extern "C" void kernel_launch(void* const* d_in, const int* in_sizes, int n_in,
                              void* d_out, int out_size, void* d_ws, size_t ws_size,
                              hipStream_t stream) {
  const float* emb    = (const float*)d_in[0];
  const float* action = (const float*)d_in[1];
  const float* reward = (const float*)d_in[2];
  const float* eps    = (const float*)d_in[3];
  const float* Wih  = (const float*)d_in[4];  const float* bih  = (const float*)d_in[5];
  const float* Whh  = (const float*)d_in[6];  const float* bhh  = (const float*)d_in[7];
  const float* stW0 = (const float*)d_in[8];  const float* stb0 = (const float*)d_in[9];
  const float* stW1 = (const float*)d_in[10]; const float* stb1 = (const float*)d_in[11];
  const float* stW2 = (const float*)d_in[12]; const float* stb2 = (const float*)d_in[13];
  const float* epW0 = (const float*)d_in[14]; const float* epb0 = (const float*)d_in[15];
  const float* epW1 = (const float*)d_in[16]; const float* epb1 = (const float*)d_in[17];
  const float* epW2 = (const float*)d_in[18]; const float* epb2 = (const float*)d_in[19];
  const float* rpW0 = (const float*)d_in[20]; const float* rpb0 = (const float*)d_in[21];
  const float* rpW1 = (const float*)d_in[22]; const float* rpb1 = (const float*)d_in[23];
  const float* rpW2 = (const float*)d_in[24]; const float* rpb2 = (const float*)d_in[25];

  double* acc = (double*)d_ws;
  // workspace (~55 MiB). eprec (16.8 MB) dead after scan; prior chunk bufs
  // (pembb 8.4 + h1b 4.2 + h2b 4.2) and ep/rp M=8192 bufs (h1c 8.4 + h2c 8.4) alias it.
  u16* states_b = (u16*)((char*)d_ws + 256);               // 16384*576*2
  float* qraw   = (float*)(states_b + (long)16384*STATE_); // 16384*128*4
  u16* eprec    = (u16*)(qraw + (long)16384*128);          // 16384*512*2
  u16* pembb = eprec;                                      // 4096*1024*2 (alias)
  u16* h1b   = pembb + (long)4096*EMB_;                    // 4096*512*2 (alias)
  u16* h2b   = h1b + (long)4096*FEAT_;                     // 4096*512*2 (alias)
  u16* h1c   = eprec;                                      // 8192*512*2 (alias)
  u16* h2c   = h1c + (long)8192*FEAT_;                     // 8192*512*2 (alias)
  float* pr2f = (float*)(eprec + (long)16384*512);         // 4096*128*4
  u16* bw = (u16*)(pr2f + (long)4096*128);
  // bf16 tail weights
  u16* bepW0 = bw;    bw += 294912;
  u16* bepW1 = bw;    bw += 262144;
  u16* bepW2 = bw;    bw += 524288;
  u16* bstW0 = bw;    bw += 786432;
  u16* bstW1 = bw;    bw += 262144;
  u16* bstW2 = bw;    bw += 65536;
  u16* brpW0 = bw;    bw += 294912;
  u16* brpW1 = bw;    bw += 262144;
  // f16 scan weights
  u16* hWhh  = bw;    bw += 786432;
  u16* hWih  = bw;    bw += 147456;
  u16* hstW0h= bw;    bw += 262144;
  u16* hstW1 = bw;    bw += 262144;
  u16* hstW2 = bw;    bw += 65536;

  hipMemsetAsync(d_ws, 0, 256, stream);

  convw_k<<<(294912+255)/256, 256, 0, stream>>>(epW0, bepW0, 294912);
  convw_k<<<(262144+255)/256, 256, 0, stream>>>(epW1, bepW1, 262144);
  convw_k<<<(524288+255)/256, 256, 0, stream>>>(epW2, bepW2, 524288);
  convw_k<<<(786432+255)/256, 256, 0, stream>>>(stW0, bstW0, 786432);
  convw_k<<<(262144+255)/256, 256, 0, stream>>>(stW1, bstW1, 262144);
  convw_k<<<(65536+255)/256,  256, 0, stream>>>(stW2, bstW2, 65536);
  convw_k<<<(294912+255)/256, 256, 0, stream>>>(rpW0, brpW0, 294912);
  convw_k<<<(262144+255)/256, 256, 0, stream>>>(rpW1, brpW1, 262144);
  convh_k<<<(786432+255)/256, 256, 0, stream>>>(Whh,  hWhh,  786432);
  convhih_k<<<(147456+255)/256, 256, 0, stream>>>(Wih, hWih);
  convh_sub_k<<<(262144+255)/256, 256, 0, stream>>>(stW0, hstW0h);
  convh_k<<<(262144+255)/256, 256, 0, stream>>>(stW1, hstW1, 262144);
  convh_k<<<(65536+255)/256,  256, 0, stream>>>(stW2, hstW2, 65536);

  // epre = emb_prev @ stW0[:,512:]^T (bf16), all 16384 rows — before the scan
  gemm_epre_k<<<128*4, 256, 0, stream>>>(emb, bstW0, eprec);

  Params p;
  p.emb = emb; p.action = action; p.reward = reward; p.eps = eps;
  p.bih = bih; p.bhh = bhh;
  p.stb0 = stb0; p.stb1 = stb1; p.stb2 = stb2;
  p.epb0 = epb0; p.epb1 = epb1; p.epb2 = epb2;
  p.hWih = hWih; p.hWhh = hWhh;
  p.hstW0h = hstW0h; p.hstW1 = hstW1; p.hstW2 = hstW2;
  p.eprec = eprec;
  p.states = states_b;
  p.qraw = qraw;
  p.acc = acc;
  p.out = (float*)d_out;

  scan_kernel<<<B_, 1024, 0, stream>>>(p);

  // ---- prior chain + KL (deferred from scan), chunks of 4096 rows ----
  for (int ch = 0; ch < 4; ++ch) {
    const u16* S    = states_b + (long)ch*4096*STATE_;
    const u16* Sprev= states_b + ((long)ch*4096 - 256)*STATE_;   // never deref'd when zlo masks
    const int zlo = (ch == 0) ? 256 : 0;
    gemm_h_k<<<32*4, 256, 0, stream>>>(Sprev, bepW0, epb0, h1b, 4, STATE_, 1, zlo);   // pe0
    gemm_h_k<<<32*4, 256, 0, stream>>>(h1b,   bepW1, epb1, h2b, 4, FEAT_, 1, 0);      // pe1
    gemm_h_k<<<32*8, 256, 0, stream>>>(h2b,   bepW2, epb2, pembb, 8, FEAT_, 0, 0);    // pemb
    gemm_cat_k<<<32*4, 256, 0, stream>>>(S, pembb, bstW0, stb0, h1b);                 // pr0
    gemm_h_k<<<32*4, 256, 0, stream>>>(h1b,   bstW1, stb1, h2b, 4, FEAT_, 1, 0);      // pr1
    gemm_raw_k<<<32, 256, 0, stream>>>(h2b, bstW2, stb2, pr2f);                        // pr2
    kl_k<<<512, 512, 0, stream>>>(qraw + (long)ch*4096*128, pr2f, acc);
  }
  // ---- ep chain: states -> h1 -> h2 -> emb loss (M=8192 chunks) ----
  for (int ch = 0; ch < 2; ++ch) {
    const u16* S = states_b + (long)ch*8192*STATE_;
    gemm_h_k<<<64*4, 256, 0, stream>>>(S,   bepW0, epb0, h1c, 4, STATE_, 1, 0);
    gemm_h_k<<<64*4, 256, 0, stream>>>(h1c, bepW1, epb1, h2c, 4, FEAT_, 1, 0);
    gemm_loss_k<<<64*8, 256, 0, stream>>>(h2c, bepW2, epb2, emb + (long)ch*8192*EMB_, 8, FEAT_, acc + 1);
  }
  // ---- rp chain (M=8192 chunks) ----
  for (int ch = 0; ch < 2; ++ch) {
    const u16* S = states_b + (long)ch*8192*STATE_;
    gemm_h_k<<<64*4, 256, 0, stream>>>(S,   brpW0, rpb0, h1c, 4, STATE_, 1, 0);
    gemm_h_k<<<64*4, 256, 0, stream>>>(h1c, brpW1, rpb1, h2c, 4, FEAT_, 1, 0);
    rp_loss_b<<<256, 512, 0, stream>>>(h2c, rpW2, rpb2, reward + (long)ch*8192, acc + 2);
  }
  final_k<<<1, 1, 0, stream>>>(acc, p.out);
}

// Round 11
// 3357.911 us; speedup vs baseline: 2.3191x; 1.4138x over previous
//
#include <hip/hip_runtime.h>
#include <math.h>

typedef unsigned short u16;
typedef unsigned char u8;
typedef __attribute__((ext_vector_type(8))) short bf16x8;
typedef __attribute__((ext_vector_type(4))) float f32x4;
typedef __attribute__((ext_vector_type(2))) _Float16 f16x2;

#define T_STEPS 64
#define B_      256
#define EMB_    1024
#define ACT_    6
#define STOCH_  64
#define HID_    512
#define FEAT_   512
#define STATE_  576
#define G3      1536
#define LOG2PI_ 1.8378770664093453

struct Params {
  const float *emb,*action,*reward,*eps;
  const float *bih,*bhh,*stb0,*stb1,*stb2,*epb0,*epb1,*epb2;
  const u16 *hWih;                                   // f16 (K=96)
  const u8  *qWhh,*qstW0h,*qstW1,*qstW2;             // int8(+128) scan weights
  const float *scWhh,*scstW0h,*scstW1,*scstW2;       // per-row scales
  const u16 *eprec;       // bf16 [T*B][512]: precomputed emb_prev @ stW0[:,512:]^T
  u16 *states;            // bf16 [T*B][STATE_]
  float *qraw;            // [T*B][128]: qmu(64) | qstd(64, post-softplus)
  double *acc;            // [0]=kl [1]=emb [2]=reward
  float *out;
};

__device__ __forceinline__ float4 ld4(const float* p){ return *(const float4*)p; }
__device__ __forceinline__ float elu_f(float x){ return x > 0.f ? x : expm1f(x); }
__device__ __forceinline__ float sigmoid_f(float x){ return 1.f/(1.f+expf(-x)); }
__device__ __forceinline__ float softplus_f(float x){ return x > 20.f ? x : log1pf(expf(x)); }
__device__ __forceinline__ float blo(unsigned u){ return __uint_as_float(u << 16); }
__device__ __forceinline__ float bhi(unsigned u){ return __uint_as_float(u & 0xFFFF0000u); }
__device__ __forceinline__ float bf2f(u16 v){ return __uint_as_float((unsigned)v << 16); }
__device__ __forceinline__ u16 f2bf(float x){     // fp32 -> bf16 RNE
  const unsigned u = __float_as_uint(x);
  return (u16)((u + 0x7FFFu + ((u>>16)&1u)) >> 16);
}
__device__ __forceinline__ u16 f2h(float x){ _Float16 h = (_Float16)x; union{_Float16 h; u16 u;} c; c.h = h; return c.u; }
__device__ __forceinline__ float h2f(u16 v){ union{u16 u; _Float16 h;} c; c.u = v; return (float)c.h; }
__device__ __forceinline__ f16x2 asf2(unsigned u){ union{unsigned u; f16x2 v;} c; c.u = u; return c.v; }
__device__ __forceinline__ float qred(float a){   // reduce over 4-lane cluster
  a += __shfl_xor(a, 1, 64);
  a += __shfl_xor(a, 2, 64);
  return a;
}
__device__ __forceinline__ double wave_sum(double v){
  #pragma unroll
  for (int o = 32; o > 0; o >>= 1) v += __shfl_down(v, o, 64);
  return v;
}

// ---------------- weight converters ----------------
__global__ void convw_k(const float* __restrict__ s, u16* __restrict__ d, int n){
  const int i = blockIdx.x*256 + threadIdx.x;
  if (i < n){
    const unsigned u = __float_as_uint(s[i]);
    d[i] = (u16)((u + 0x7FFFu + ((u>>16)&1u)) >> 16);
  }
}
// Wih [1536][70] -> padded [1536][96] f16 (zero pad)
__global__ void convhih_k(const float* __restrict__ s, u16* __restrict__ d){
  const int i = blockIdx.x*256 + threadIdx.x;   // < 1536*96
  const int n = i/96, k = i%96;
  d[i] = (k < 70) ? f2h(s[n*70 + k]) : (u16)0;
}
// R16: int8 per-row symmetric quantization of W[N][512] (src row stride SK).
// store u8 = round(w*127/max)+128; scale[n] = max/127.
__global__ void __launch_bounds__(256) convq_k(const float* __restrict__ s, int SK,
                                               u8* __restrict__ d, float* __restrict__ sc){
  const int n = blockIdx.x, t = threadIdx.x;
  __shared__ float red[256];
  red[t] = fmaxf(fabsf(s[(long)n*SK + t]), fabsf(s[(long)n*SK + t + 256]));
  __syncthreads();
  for (int o = 128; o > 0; o >>= 1){
    if (t < o) red[t] = fmaxf(red[t], red[t+o]);
    __syncthreads();
  }
  const float mx = fmaxf(red[0], 1e-20f);
  if (t == 0) sc[n] = mx / 127.f;
  const float inv = 127.f / mx;
  for (int k = t; k < 512; k += 256){
    float q = rintf(s[(long)n*SK + k] * inv);
    q = fminf(fmaxf(q, -127.f), 127.f);
    d[(long)n*512 + k] = (u8)(int)(q + 128.f);
  }
}

// ---------------- scan GEMV cores ----------------
// f16 core (R7-proven) — used for gi (K=96) only.
template<int K>
__device__ __forceinline__ void gemv2h(const u16* __restrict__ W, const u16* __restrict__ x,
                                       int n0, int n1, int l, float& y0, float& y1){
  const u16* w0 = W + (long)n0*K + l*8;
  const u16* w1 = W + (long)n1*K + l*8;
  const u16* xr = x + l*8;
  float a0=0.f, a1=0.f, b0=0.f, b1=0.f;
  for (int j = 0; j < K/32; ++j){
    const uint4 a  = *(const uint4*)(w0 + 32*j);
    const uint4 b  = *(const uint4*)(w1 + 32*j);
    const uint4 xv = *(const uint4*)(xr + 32*j);
    a0 = __builtin_amdgcn_fdot2(asf2(a.x), asf2(xv.x), a0, false);
    a1 = __builtin_amdgcn_fdot2(asf2(a.y), asf2(xv.y), a1, false);
    a0 = __builtin_amdgcn_fdot2(asf2(a.z), asf2(xv.z), a0, false);
    a1 = __builtin_amdgcn_fdot2(asf2(a.w), asf2(xv.w), a1, false);
    b0 = __builtin_amdgcn_fdot2(asf2(b.x), asf2(xv.x), b0, false);
    b1 = __builtin_amdgcn_fdot2(asf2(b.y), asf2(xv.y), b1, false);
    b0 = __builtin_amdgcn_fdot2(asf2(b.z), asf2(xv.z), b0, false);
    b1 = __builtin_amdgcn_fdot2(asf2(b.w), asf2(xv.w), b1, false);
  }
  y0 = qred(a0 + a1);
  y1 = qred(b0 + b1);
}

// R16 int8 core: one uint4 carries 16 weights (2x the f16 density) -> global load
// count per row HALVES (8 vs 16). Unpack: v_perm builds f16 halves 0x6400|byte
// (= 1024+u exactly), one pk_add of -1152 -> exact int-valued f16 in [-127,127].
__device__ __forceinline__ float dotq(unsigned w4, unsigned xlo, unsigned xhi,
                                      f16x2 mk, float acc){
  const unsigned plo = __builtin_amdgcn_perm(0x64646464u, w4, 0x05010400u); // {k0,k1}
  const unsigned phi = __builtin_amdgcn_perm(0x64646464u, w4, 0x05030402u); // {k2,k3}
  const f16x2 wlo = asf2(plo) + mk;
  const f16x2 whi = asf2(phi) + mk;
  acc = __builtin_amdgcn_fdot2(wlo, asf2(xlo), acc, false);
  acc = __builtin_amdgcn_fdot2(whi, asf2(xhi), acc, false);
  return acc;
}
// K=512 fixed. lane l covers k = l*16 + 64*j (16 int8 = one uint4 per stream per j).
__device__ __forceinline__ void gemv2q(const u8* __restrict__ W, const float* __restrict__ sc,
                                       const u16* __restrict__ x,
                                       int n0, int n1, int l, float& y0, float& y1){
  const u8* w0 = W + (long)n0*512 + l*16;
  const u8* w1 = W + (long)n1*512 + l*16;
  const u16* xr = x + l*16;
  const f16x2 mk = {(_Float16)(-1152.f), (_Float16)(-1152.f)};
  float a0=0.f, a1=0.f;
  for (int j = 0; j < 8; ++j){
    const uint4 wa = *(const uint4*)(w0 + 64*j);
    const uint4 wb = *(const uint4*)(w1 + 64*j);
    const uint4 x0 = *(const uint4*)(xr + 64*j);
    const uint4 x1 = *(const uint4*)(xr + 64*j + 8);
    a0 = dotq(wa.x, x0.x, x0.y, mk, a0);
    a0 = dotq(wa.y, x0.z, x0.w, mk, a0);
    a0 = dotq(wa.z, x1.x, x1.y, mk, a0);
    a0 = dotq(wa.w, x1.z, x1.w, mk, a0);
    b_stream:
    a1 = dotq(wb.x, x0.x, x0.y, mk, a1);
    a1 = dotq(wb.y, x0.z, x0.w, mk, a1);
    a1 = dotq(wb.z, x1.x, x1.y, mk, a1);
    a1 = dotq(wb.w, x1.z, x1.w, mk, a1);
  }
  y0 = qred(a0) * sc[n0];
  y1 = qred(a1) * sc[n1];
}

// ---------------- scan kernel: 1024 thr, R7 phases + int8 K=512 weights (R16) ------
__global__ void __launch_bounds__(1024) scan_kernel(Params p)
{
  const int tid = threadIdx.x;
  const int r = blockIdx.x;
  const int c = tid >> 2, l = tid & 3;   // 256 clusters of 4 lanes

  __shared__ __align__(16) u16 hsh[STATE_];    // f16 [h(512) | s(64)]
  __shared__ __align__(16) u16 sah[96];        // f16 [s(64) | a(6) | 0-pad]
  __shared__ __align__(16) float gi[G3], gh[G3];
  __shared__ __align__(16) u16 po0h[512], po1h[512];   // f16
  __shared__ __align__(16) float po2[128];

  if (tid < STATE_) hsh[tid] = 0;
  __syncthreads();

  for (int t = 0; t < T_STEPS; ++t){
    // ---- prologue: sa = [s_{t-1} | a_t | 0] (f16) ----
    if (tid < 96){
      u16 v = 0;
      if (tid < 64)      v = hsh[512 + tid];
      else if (tid < 70) v = f2h(p.action[((long)t*B_ + r)*ACT_ + (tid - 64)]);
      sah[tid] = v;
    }
    __syncthreads();
    // ---- gh (3p, int8), gi (3p, f16) ----
    #pragma unroll
    for (int ps = 0; ps < 3; ++ps){
      const int n0 = ps*512 + c, n1 = n0 + 256;
      float y0, y1;
      gemv2q(p.qWhh, p.scWhh, hsh, n0, n1, l, y0, y1);
      if (l == 0){
        gh[n0] = y0 + p.bhh[n0];
        gh[n1] = y1 + p.bhh[n1];
      }
    }
    #pragma unroll
    for (int ps = 0; ps < 3; ++ps){
      const int n0 = ps*512 + c, n1 = n0 + 256;
      float y0, y1;
      gemv2h<96>(p.hWih, sah, n0, n1, l, y0, y1);
      if (l == 0){
        gi[n0] = y0 + p.bih[n0];
        gi[n1] = y1 + p.bih[n1];
      }
    }
    __syncthreads();
    // ---- GRU combine -> h_t ----
    if (tid < 512){
      const int j = tid;
      const float ir = gi[j], iz = gi[512+j], in_ = gi[1024+j];
      const float hr = gh[j], hz = gh[512+j], hn  = gh[1024+j];
      const float rr = sigmoid_f(ir + hr);
      const float z  = sigmoid_f(iz + hz);
      const float nn = tanhf(in_ + rr*hn);
      const float hv = (1.f - z)*nn + z*h2f(hsh[j]);
      hsh[j] = f2h(hv);
      p.states[((long)t*B_ + r)*STATE_ + j] = f2bf(hv);
    }
    __syncthreads();
    // ---- st0 posterior h-head (int8) + precomputed emb-tail ----
    {
      const int n0 = c, n1 = c + 256;
      float y0, y1;
      gemv2q(p.qstW0h, p.scstW0h, hsh, n0, n1, l, y0, y1);
      if (l == 0){
        const u16* ep = p.eprec + ((long)t*B_ + r)*512;
        po0h[n0] = f2h(elu_f(y0 + p.stb0[n0] + bf2f(ep[n0])));
        po0h[n1] = f2h(elu_f(y1 + p.stb0[n1] + bf2f(ep[n1])));
      }
    }
    __syncthreads();
    // ---- st1 posterior (int8) ----
    {
      const int n0 = c, n1 = c + 256;
      float y0, y1;
      gemv2q(p.qstW1, p.scstW1, po0h, n0, n1, l, y0, y1);
      if (l == 0){
        po1h[n0] = f2h(elu_f(y0 + p.stb1[n0]));
        po1h[n1] = f2h(elu_f(y1 + p.stb1[n1]));
      }
    }
    __syncthreads();
    // ---- st2 posterior (int8, clusters 0..63) ----
    if (c < 64){
      const int n0 = c, n1 = c + 64;
      float y0, y1;
      gemv2q(p.qstW2, p.scstW2, po1h, n0, n1, l, y0, y1);
      if (l == 0){
        po2[n0] = y0 + p.stb2[n0];
        po2[n1] = y1 + p.stb2[n1];
      }
    }
    __syncthreads();
    // ---- sample s_t, store qmu/qstd ----
    if (tid < 64){
      const int j = tid;
      const float qmu = po2[j],  qsr = po2[64+j];
      const float qstd = softplus_f(qsr) + 1e-4f;
      const float sv = qmu + qstd * p.eps[((long)t*B_ + r)*STOCH_ + j];
      hsh[512 + j] = f2h(sv);
      p.states[((long)t*B_ + r)*STATE_ + 512 + j] = f2bf(sv);
      p.qraw[((long)t*B_ + r)*128 + j]      = qmu;
      p.qraw[((long)t*B_ + r)*128 + 64 + j] = qstd;
    }
    __syncthreads();
  }
}

// ---------------- epre GEMM: emb_prev (fp32, in-reg cvt) @ stW0[:,512:]^T -> bf16 ----
__global__ void __launch_bounds__(256) gemm_epre_k(const float* __restrict__ E,
                                                   const u16* __restrict__ W,   // bstW0 full
                                                   u16* __restrict__ Y)
{
  const int NT = 4;
  const int tid = threadIdx.x;
  const int wave = tid >> 6, lane = tid & 63;
  const int bm = blockIdx.x / NT, bn = blockIdx.x % NT;
  const int row0 = bm*128 + ((wave>>1)<<6);
  const int col0 = bn*128 + ((wave&1)<<6);
  const int lr = lane & 15, lk = (lane >> 4) * 8;
  f32x4 acc[4][4] = {};
  for (int k0 = 0; k0 < EMB_; k0 += 32){
    bf16x8 a[4], b[4];
    #pragma unroll
    for (int i = 0; i < 4; ++i){
      const int row = row0 + 16*i + lr;
      const int arow = row - (row >= B_ ? B_ : 0);   // emb_prev shift (128-blocks never straddle)
      const float* src = E + (long)arow*EMB_ + k0 + lk;
      const float4 f0 = ld4(src), f1 = ld4(src + 4);
      bf16x8 v;
      v[0] = (short)f2bf(f0.x); v[1] = (short)f2bf(f0.y);
      v[2] = (short)f2bf(f0.z); v[3] = (short)f2bf(f0.w);
      v[4] = (short)f2bf(f1.x); v[5] = (short)f2bf(f1.y);
      v[6] = (short)f2bf(f1.z); v[7] = (short)f2bf(f1.w);
      a[i] = v;
    }
    #pragma unroll
    for (int j = 0; j < 4; ++j)
      b[j] = *(const bf16x8*)(W + (long)(col0+16*j+lr)*G3 + 512 + k0 + lk);
    #pragma unroll
    for (int i = 0; i < 4; ++i)
      #pragma unroll
      for (int j = 0; j < 4; ++j)
        acc[i][j] = __builtin_amdgcn_mfma_f32_16x16x32_bf16(a[i], b[j], acc[i][j], 0, 0, 0);
  }
  #pragma unroll
  for (int j = 0; j < 4; ++j){
    const int col = col0 + 16*j + lr;
    #pragma unroll
    for (int i = 0; i < 4; ++i)
      #pragma unroll
      for (int q = 0; q < 4; ++q){
        const int row = row0 + 16*i + (lane>>4)*4 + q;
        Y[(long)row*512 + col] = f2bf(acc[i][j][q]);
      }
  }
}

// ---------------- MFMA bf16 tail GEMMs (R10-proven, byte-identical) -----------------

__global__ void __launch_bounds__(256) gemm_h_k(const u16* __restrict__ A,
                                                const u16* __restrict__ W,
                                                const float* __restrict__ bias,
                                                u16* __restrict__ Y,
                                                int NT, int K, int act, int zlo)
{
  const int tid = threadIdx.x;
  const int wave = tid >> 6, lane = tid & 63;
  const int bm = blockIdx.x / NT, bn = blockIdx.x % NT;
  const int row0 = bm*128 + ((wave>>1)<<6);
  const int col0 = bn*128 + ((wave&1)<<6);
  const int lr = lane & 15, lk = (lane >> 4) * 8;
  const int N = NT << 7;
  f32x4 acc[4][4] = {};
  const u16* Ab = A + (long)row0*K + lk;
  const u16* Wb = W + (long)col0*K + lk;
  const bf16x8 zf = {};
  for (int k0 = 0; k0 < K; k0 += 32){
    bf16x8 a[4], b[4];
    #pragma unroll
    for (int i = 0; i < 4; ++i)
      a[i] = (row0 + 16*i >= zlo) ? *(const bf16x8*)(Ab + (long)(16*i+lr)*K + k0) : zf;
    #pragma unroll
    for (int j = 0; j < 4; ++j) b[j] = *(const bf16x8*)(Wb + (long)(16*j+lr)*K + k0);
    #pragma unroll
    for (int i = 0; i < 4; ++i)
      #pragma unroll
      for (int j = 0; j < 4; ++j)
        acc[i][j] = __builtin_amdgcn_mfma_f32_16x16x32_bf16(a[i], b[j], acc[i][j], 0, 0, 0);
  }
  #pragma unroll
  for (int j = 0; j < 4; ++j){
    const int col = col0 + 16*j + lr;
    const float bv = bias[col];
    #pragma unroll
    for (int i = 0; i < 4; ++i){
      #pragma unroll
      for (int q = 0; q < 4; ++q){
        const int row = row0 + 16*i + (lane>>4)*4 + q;
        float v = acc[i][j][q] + bv;
        if (act) v = elu_f(v);
        Y[(long)row*N + col] = f2bf(v);
      }
    }
  }
}

// st0 prior: A = [states.h (ld 576, k<512) | pemb (ld 1024, k>=512)], W [512][1536], elu out
__global__ void __launch_bounds__(256) gemm_cat_k(const u16* __restrict__ A1,
                                                  const u16* __restrict__ A2,
                                                  const u16* __restrict__ W,
                                                  const float* __restrict__ bias,
                                                  u16* __restrict__ Y)
{
  const int NT = 4;
  const int tid = threadIdx.x;
  const int wave = tid >> 6, lane = tid & 63;
  const int bm = blockIdx.x / NT, bn = blockIdx.x % NT;
  const int row0 = bm*128 + ((wave>>1)<<6);
  const int col0 = bn*128 + ((wave&1)<<6);
  const int lr = lane & 15, lk = (lane >> 4) * 8;
  f32x4 acc[4][4] = {};
  for (int k0 = 0; k0 < G3; k0 += 32){
    bf16x8 a[4], b[4];
    #pragma unroll
    for (int i = 0; i < 4; ++i){
      const long row = row0 + 16*i + lr;
      a[i] = (k0 < 512) ? *(const bf16x8*)(A1 + row*STATE_ + k0 + lk)
                        : *(const bf16x8*)(A2 + row*EMB_ + (k0-512) + lk);
    }
    #pragma unroll
    for (int j = 0; j < 4; ++j)
      b[j] = *(const bf16x8*)(W + (long)(col0+16*j+lr)*G3 + k0 + lk);
    #pragma unroll
    for (int i = 0; i < 4; ++i)
      #pragma unroll
      for (int j = 0; j < 4; ++j)
        acc[i][j] = __builtin_amdgcn_mfma_f32_16x16x32_bf16(a[i], b[j], acc[i][j], 0, 0, 0);
  }
  #pragma unroll
  for (int j = 0; j < 4; ++j){
    const int col = col0 + 16*j + lr;
    const float bv = bias[col];
    #pragma unroll
    for (int i = 0; i < 4; ++i){
      #pragma unroll
      for (int q = 0; q < 4; ++q){
        const int row = row0 + 16*i + (lane>>4)*4 + q;
        Y[(long)row*FEAT_ + col] = f2bf(elu_f(acc[i][j][q] + bv));
      }
    }
  }
}

// st2 prior: N=128, K=512, raw f32 out (+bias, no act). grid = M/128 blocks.
__global__ void __launch_bounds__(256) gemm_raw_k(const u16* __restrict__ A,
                                                  const u16* __restrict__ W,
                                                  const float* __restrict__ bias,
                                                  float* __restrict__ Y)
{
  const int tid = threadIdx.x;
  const int wave = tid >> 6, lane = tid & 63;
  const int row0 = blockIdx.x*128 + ((wave>>1)<<6);
  const int col0 = (wave&1)<<6;
  const int lr = lane & 15, lk = (lane >> 4) * 8;
  f32x4 acc[4][4] = {};
  const u16* Ab = A + (long)row0*FEAT_ + lk;
  const u16* Wb = W + (long)col0*FEAT_ + lk;
  for (int k0 = 0; k0 < FEAT_; k0 += 32){
    bf16x8 a[4], b[4];
    #pragma unroll
    for (int i = 0; i < 4; ++i) a[i] = *(const bf16x8*)(Ab + (long)(16*i+lr)*FEAT_ + k0);
    #pragma unroll
    for (int j = 0; j < 4; ++j) b[j] = *(const bf16x8*)(Wb + (long)(16*j+lr)*FEAT_ + k0);
    #pragma unroll
    for (int i = 0; i < 4; ++i)
      #pragma unroll
      for (int j = 0; j < 4; ++j)
        acc[i][j] = __builtin_amdgcn_mfma_f32_16x16x32_bf16(a[i], b[j], acc[i][j], 0, 0, 0);
  }
  #pragma unroll
  for (int j = 0; j < 4; ++j){
    const int col = col0 + 16*j + lr;
    const float bv = bias[col];
    #pragma unroll
    for (int i = 0; i < 4; ++i){
      #pragma unroll
      for (int q = 0; q < 4; ++q){
        const int row = row0 + 16*i + (lane>>4)*4 + q;
        Y[(long)row*128 + col] = acc[i][j][q] + bv;
      }
    }
  }
}

// KL over one 4096-row chunk: q = stored qmu/qstd, pr = prior raw (pmu, psr).
__global__ void __launch_bounds__(512) kl_k(const float* __restrict__ q,
                                            const float* __restrict__ pr,
                                            double* accp)
{
  const int idx = blockIdx.x*512 + threadIdx.x;   // < 4096*64
  const int row = idx >> 6, j = idx & 63;
  const float qmu = q[row*128 + j], qstd = q[row*128 + 64 + j];
  const float pmu = pr[row*128 + j], psr = pr[row*128 + 64 + j];
  const float pstd = softplus_f(psr) + 1e-4f;
  const float dm = qmu - pmu;
  double v = (double)(logf(pstd/qstd) + (qstd*qstd + dm*dm)/(2.f*pstd*pstd) - 0.5f);
  v = wave_sum(v);
  if ((threadIdx.x & 63) == 0) atomicAdd(accp, v);
}

__device__ __forceinline__ double wave_sum_d(double v){
  #pragma unroll
  for (int o = 32; o > 0; o >>= 1) v += __shfl_down(v, o, 64);
  return v;
}

__global__ void __launch_bounds__(256) gemm_loss_k(const u16* __restrict__ A,
                                                   const u16* __restrict__ W,
                                                   const float* __restrict__ bias,
                                                   const float* __restrict__ tgt,
                                                   int NT, int K, double* accp)
{
  const int tid = threadIdx.x;
  const int wave = tid >> 6, lane = tid & 63;
  const int bm = blockIdx.x / NT, bn = blockIdx.x % NT;
  const int row0 = bm*128 + ((wave>>1)<<6);
  const int col0 = bn*128 + ((wave&1)<<6);
  const int lr = lane & 15, lk = (lane >> 4) * 8;
  const int N = NT << 7;
  f32x4 acc[4][4] = {};
  const u16* Ab = A + (long)row0*K + lk;
  const u16* Wb = W + (long)col0*K + lk;
  for (int k0 = 0; k0 < K; k0 += 32){
    bf16x8 a[4], b[4];
    #pragma unroll
    for (int i = 0; i < 4; ++i) a[i] = *(const bf16x8*)(Ab + (long)(16*i+lr)*K + k0);
    #pragma unroll
    for (int j = 0; j < 4; ++j) b[j] = *(const bf16x8*)(Wb + (long)(16*j+lr)*K + k0);
    #pragma unroll
    for (int i = 0; i < 4; ++i)
      #pragma unroll
      for (int j = 0; j < 4; ++j)
        acc[i][j] = __builtin_amdgcn_mfma_f32_16x16x32_bf16(a[i], b[j], acc[i][j], 0, 0, 0);
  }
  double ls = 0.0;
  #pragma unroll
  for (int j = 0; j < 4; ++j){
    const int col = col0 + 16*j + lr;
    const float bv = bias[col];
    #pragma unroll
    for (int i = 0; i < 4; ++i){
      #pragma unroll
      for (int q = 0; q < 4; ++q){
        const int row = row0 + 16*i + (lane>>4)*4 + q;
        const float d = tgt[(long)row*N + col] - (acc[i][j][q] + bv);
        ls += 0.5 * (double)d * (double)d;
      }
    }
  }
  ls = wave_sum_d(ls);
  if (lane == 0) atomicAdd(accp, ls);
}

// reward head over one 8192-row chunk.
__global__ void __launch_bounds__(512) rp_loss_b(const u16* __restrict__ h2,
                                                 const float* __restrict__ W2,
                                                 const float* __restrict__ b2,
                                                 const float* __restrict__ reward,
                                                 double* accp)
{
  const int tid = threadIdx.x;
  const int lane = tid & 63;
  const int wid = blockIdx.x*8 + (tid >> 6);
  double ls = 0.0;
  for (int row = wid; row < 8192; row += 2048) {
    const uint4 hv = *(const uint4*)(h2 + (long)row*FEAT_ + lane*8);
    const float4 w0 = ld4(W2 + lane*8);
    const float4 w1 = ld4(W2 + lane*8 + 4);
    float part = blo(hv.x)*w0.x + bhi(hv.x)*w0.y + blo(hv.y)*w0.z + bhi(hv.y)*w0.w
               + blo(hv.z)*w1.x + bhi(hv.z)*w1.y + blo(hv.w)*w1.z + bhi(hv.w)*w1.w;
    #pragma unroll
    for (int o = 32; o > 0; o >>= 1) part += __shfl_down(part, o, 64);
    if (lane == 0) {
      const float mu = part + b2[0];
      const float d = reward[row] - mu;
      ls += 0.5 * (double)d * (double)d;
    }
  }
  if (lane == 0) atomicAdd(accp, ls);
}

__global__ void final_k(const double* acc, float* out)
{
  const double tot = (acc[0] + acc[1] + acc[2]) / (double)(T_STEPS * B_)
                   + 512.0 * LOG2PI_ + 0.5 * LOG2PI_;
  out[0] = (float)tot;
}

extern "C" void kernel_launch(void* const* d_in, const int* in_sizes, int n_in,
                              void* d_out, int out_size, void* d_ws, size_t ws_size,
                              hipStream_t stream) {
  const float* emb    = (const float*)d_in[0];
  const float* action = (const float*)d_in[1];
  const float* reward = (const float*)d_in[2];
  const float* eps    = (const float*)d_in[3];
  const float* Wih  = (const float*)d_in[4];  const float* bih  = (const float*)d_in[5];
  const float* Whh  = (const float*)d_in[6];  const float* bhh  = (const float*)d_in[7];
  const float* stW0 = (const float*)d_in[8];  const float* stb0 = (const float*)d_in[9];
  const float* stW1 = (const float*)d_in[10]; const float* stb1 = (const float*)d_in[11];
  const float* stW2 = (const float*)d_in[12]; const float* stb2 = (const float*)d_in[13];
  const float* epW0 = (const float*)d_in[14]; const float* epb0 = (const float*)d_in[15];
  const float* epW1 = (const float*)d_in[16]; const float* epb1 = (const float*)d_in[17];
  const float* epW2 = (const float*)d_in[18]; const float* epb2 = (const float*)d_in[19];
  const float* rpW0 = (const float*)d_in[20]; const float* rpb0 = (const float*)d_in[21];
  const float* rpW1 = (const float*)d_in[22]; const float* rpb1 = (const float*)d_in[23];
  const float* rpW2 = (const float*)d_in[24]; const float* rpb2 = (const float*)d_in[25];

  double* acc = (double*)d_ws;
  // workspace (~54 MiB). eprec (16.8 MB) dead after scan; prior chunk bufs
  // (pembb 8.4 + h1b 4.2 + h2b 4.2) and ep/rp M=8192 bufs (h1c 8.4 + h2c 8.4) alias it.
  u16* states_b = (u16*)((char*)d_ws + 256);               // 16384*576*2
  float* qraw   = (float*)(states_b + (long)16384*STATE_); // 16384*128*4
  u16* eprec    = (u16*)(qraw + (long)16384*128);          // 16384*512*2
  u16* pembb = eprec;                                      // 4096*1024*2 (alias)
  u16* h1b   = pembb + (long)4096*EMB_;                    // 4096*512*2 (alias)
  u16* h2b   = h1b + (long)4096*FEAT_;                     // 4096*512*2 (alias)
  u16* h1c   = eprec;                                      // 8192*512*2 (alias)
  u16* h2c   = h1c + (long)8192*FEAT_;                     // 8192*512*2 (alias)
  float* pr2f = (float*)(eprec + (long)16384*512);         // 4096*128*4
  u16* bw = (u16*)(pr2f + (long)4096*128);
  // bf16 tail weights
  u16* bepW0 = bw;    bw += 294912;
  u16* bepW1 = bw;    bw += 262144;
  u16* bepW2 = bw;    bw += 524288;
  u16* bstW0 = bw;    bw += 786432;
  u16* bstW1 = bw;    bw += 262144;
  u16* bstW2 = bw;    bw += 65536;
  u16* brpW0 = bw;    bw += 294912;
  u16* brpW1 = bw;    bw += 262144;
  // f16 gi weights + int8 scan weights + per-row scales
  u16* hWih  = bw;    bw += 147456;
  u8* qb = (u8*)bw;
  u8* qWhh   = qb;    qb += 786432;   // 1536*512
  u8* qstW0h = qb;    qb += 262144;   // 512*512
  u8* qstW1  = qb;    qb += 262144;
  u8* qstW2  = qb;    qb += 65536;    // 128*512
  float* scWhh   = (float*)qb;  qb += 1536*4;
  float* scstW0h = (float*)qb;  qb += 512*4;
  float* scstW1  = (float*)qb;  qb += 512*4;
  float* scstW2  = (float*)qb;  qb += 128*4;

  hipMemsetAsync(d_ws, 0, 256, stream);

  convw_k<<<(294912+255)/256, 256, 0, stream>>>(epW0, bepW0, 294912);
  convw_k<<<(262144+255)/256, 256, 0, stream>>>(epW1, bepW1, 262144);
  convw_k<<<(524288+255)/256, 256, 0, stream>>>(epW2, bepW2, 524288);
  convw_k<<<(786432+255)/256, 256, 0, stream>>>(stW0, bstW0, 786432);
  convw_k<<<(262144+255)/256, 256, 0, stream>>>(stW1, bstW1, 262144);
  convw_k<<<(65536+255)/256,  256, 0, stream>>>(stW2, bstW2, 65536);
  convw_k<<<(294912+255)/256, 256, 0, stream>>>(rpW0, brpW0, 294912);
  convw_k<<<(262144+255)/256, 256, 0, stream>>>(rpW1, brpW1, 262144);
  convhih_k<<<(147456+255)/256, 256, 0, stream>>>(Wih, hWih);
  // int8 scan weights (per-row scale)
  convq_k<<<1536, 256, 0, stream>>>(Whh,  512, qWhh,   scWhh);
  convq_k<<<512,  256, 0, stream>>>(stW0, G3,  qstW0h, scstW0h);
  convq_k<<<512,  256, 0, stream>>>(stW1, 512, qstW1,  scstW1);
  convq_k<<<128,  256, 0, stream>>>(stW2, 512, qstW2,  scstW2);

  // epre = emb_prev @ stW0[:,512:]^T (bf16), all 16384 rows — before the scan
  gemm_epre_k<<<128*4, 256, 0, stream>>>(emb, bstW0, eprec);

  Params p;
  p.emb = emb; p.action = action; p.reward = reward; p.eps = eps;
  p.bih = bih; p.bhh = bhh;
  p.stb0 = stb0; p.stb1 = stb1; p.stb2 = stb2;
  p.epb0 = epb0; p.epb1 = epb1; p.epb2 = epb2;
  p.hWih = hWih;
  p.qWhh = qWhh; p.qstW0h = qstW0h; p.qstW1 = qstW1; p.qstW2 = qstW2;
  p.scWhh = scWhh; p.scstW0h = scstW0h; p.scstW1 = scstW1; p.scstW2 = scstW2;
  p.eprec = eprec;
  p.states = states_b;
  p.qraw = qraw;
  p.acc = acc;
  p.out = (float*)d_out;

  scan_kernel<<<B_, 1024, 0, stream>>>(p);

  // ---- prior chain + KL (deferred from scan), chunks of 4096 rows ----
  for (int ch = 0; ch < 4; ++ch) {
    const u16* S    = states_b + (long)ch*4096*STATE_;
    const u16* Sprev= states_b + ((long)ch*4096 - 256)*STATE_;   // never deref'd when zlo masks
    const int zlo = (ch == 0) ? 256 : 0;
    gemm_h_k<<<32*4, 256, 0, stream>>>(Sprev, bepW0, epb0, h1b, 4, STATE_, 1, zlo);   // pe0
    gemm_h_k<<<32*4, 256, 0, stream>>>(h1b,   bepW1, epb1, h2b, 4, FEAT_, 1, 0);      // pe1
    gemm_h_k<<<32*8, 256, 0, stream>>>(h2b,   bepW2, epb2, pembb, 8, FEAT_, 0, 0);    // pemb
    gemm_cat_k<<<32*4, 256, 0, stream>>>(S, pembb, bstW0, stb0, h1b);                 // pr0
    gemm_h_k<<<32*4, 256, 0, stream>>>(h1b,   bstW1, stb1, h2b, 4, FEAT_, 1, 0);      // pr1
    gemm_raw_k<<<32, 256, 0, stream>>>(h2b, bstW2, stb2, pr2f);                        // pr2
    kl_k<<<512, 512, 0, stream>>>(qraw + (long)ch*4096*128, pr2f, acc);
  }
  // ---- ep chain: states -> h1 -> h2 -> emb loss (M=8192 chunks) ----
  for (int ch = 0; ch < 2; ++ch) {
    const u16* S = states_b + (long)ch*8192*STATE_;
    gemm_h_k<<<64*4, 256, 0, stream>>>(S,   bepW0, epb0, h1c, 4, STATE_, 1, 0);
    gemm_h_k<<<64*4, 256, 0, stream>>>(h1c, bepW1, epb1, h2c, 4, FEAT_, 1, 0);
    gemm_loss_k<<<64*8, 256, 0, stream>>>(h2c, bepW2, epb2, emb + (long)ch*8192*EMB_, 8, FEAT_, acc + 1);
  }
  // ---- rp chain (M=8192 chunks) ----
  for (int ch = 0; ch < 2; ++ch) {
    const u16* S = states_b + (long)ch*8192*STATE_;
    gemm_h_k<<<64*4, 256, 0, stream>>>(S,   brpW0, rpb0, h1c, 4, STATE_, 1, 0);
    gemm_h_k<<<64*4, 256, 0, stream>>>(h1c, brpW1, rpb1, h2c, 4, FEAT_, 1, 0);
    rp_loss_b<<<256, 512, 0, stream>>>(h2c, rpW2, rpb2, reward + (long)ch*8192, acc + 2);
  }
  final_k<<<1, 1, 0, stream>>>(acc, p.out);
}